// Round 1
// baseline (2051.338 us; speedup 1.0000x reference)
//
#include <hip/hip_runtime.h>
#include <hip/hip_bf16.h>
#include <cstdint>
#include <cstddef>

// Sizes (from reference): N=20000, E=100000, G=32, HID=64, HEADS=8, HC=64, HO=512, L=3, K=4
// All fp32. Wave=64. Strategy: fused per-edge kernels, wave=4 edges, lane owns 8 cols
// (one col-octet inside a single head), shfl reductions for head dots / head means.

__device__ __forceinline__ unsigned fkey(float f) {
    unsigned u = __float_as_uint(f);
    return (u & 0x80000000u) ? ~u : (u | 0x80000000u);
}
__device__ __forceinline__ float funkey(unsigned kk) {
    unsigned u = (kk & 0x80000000u) ? (kk & 0x7FFFFFFFu) : ~kk;
    return __uint_as_float(u);
}

// h = relu(x @ ne_W + ne_b)   x: N x 7, ne_W: 7 x 64
__global__ void __launch_bounds__(256) k_node_embed(
    const float* __restrict__ x, const float* __restrict__ neW, const float* __restrict__ neb,
    float* __restrict__ h, int N)
{
    int idx = blockIdx.x * 256 + threadIdx.x;
    int n = idx >> 6, c = idx & 63;
    if (n >= N) return;
    float acc = neb[c];
    #pragma unroll
    for (int j = 0; j < 7; ++j) acc += x[(size_t)n * 7 + j] * neW[j * 64 + c];
    h[(size_t)n * 64 + c] = fmaxf(acc, 0.f);
}

// ea = relu(edge_attr @ ee_W + ee_b) + relu(w @ sp_W + sp_b), w from gaussian dists
__global__ void __launch_bounds__(256) k_edge_init(
    const float* __restrict__ x, const float* __restrict__ edge_attr,
    const float* __restrict__ means, const float* __restrict__ log_stds,
    const float* __restrict__ spW, const float* __restrict__ spb,
    const float* __restrict__ eeW, const float* __restrict__ eeb,
    const int* __restrict__ src, const int* __restrict__ dst,
    float* __restrict__ ea, int E)
{
    int gw = (blockIdx.x * 256 + threadIdx.x) >> 6;
    int lane = threadIdx.x & 63;
    if (gw >= E) return;
    int s = src[gw], d = dst[gw];
    const float* ps = x + (size_t)s * 7;
    const float* pd = x + (size_t)d * 7;
    float slx = ps[0], sly = ps[1], srx = ps[2], sry = ps[3];
    float dlx = pd[0], dly = pd[1], drx = pd[2], dry = pd[3];
    float u[8];
    float rx, ry;
    rx = dlx - slx; ry = dly - sly; u[0] = sqrtf(rx*rx + ry*ry); u[1] = atan2f(ry, rx);
    rx = dlx - srx; ry = dly - sry; u[2] = sqrtf(rx*rx + ry*ry); u[3] = atan2f(ry, rx);
    rx = drx - slx; ry = dry - sly; u[4] = sqrtf(rx*rx + ry*ry); u[5] = atan2f(ry, rx);
    rx = drx - srx; ry = dry - sry; u[6] = sqrtf(rx*rx + ry*ry); u[7] = atan2f(ry, rx);
    float w[4];
    #pragma unroll
    for (int kk = 0; kk < 4; ++kk) {
        float ssum = 0.f;
        #pragma unroll
        for (int dd = 0; dd < 8; ++dd) {
            float stdv = expf(log_stds[kk*8+dd]) + 1e-6f;
            float z = (u[dd] - means[kk*8+dd]) / stdv;
            ssum += z * z;
        }
        w[kk] = expf(-0.5f * ssum);
    }
    float accs = spb[lane];
    #pragma unroll
    for (int kk = 0; kk < 4; ++kk) accs += w[kk] * spW[kk*64 + lane];
    float acce = eeb[lane];
    #pragma unroll
    for (int j = 0; j < 4; ++j) acce += edge_attr[(size_t)gw*4 + j] * eeW[j*64 + lane];
    ea[(size_t)gw*64 + lane] = fmaxf(acce, 0.f) + fmaxf(accs, 0.f);
}

// Y = X @ W + bias  (X: M x 64, W: 64 x 512). Block=256 -> 16 rows, wave=4 rows, lane=8 cols.
__global__ void __launch_bounds__(256) k_gemm512(
    const float* __restrict__ X, const float* __restrict__ W, const float* __restrict__ bias,
    float* __restrict__ Y, int M)
{
    __shared__ __align__(16) float xs[16][64];
    int tid = threadIdx.x;
    int r0 = blockIdx.x * 16;
    for (int i = tid; i < 1024; i += 256) {
        int r = i >> 6, c = i & 63;
        int rr = r0 + r;
        xs[r][c] = (rr < M) ? X[(size_t)rr * 64 + c] : 0.f;
    }
    __syncthreads();
    int wv = tid >> 6, lane = tid & 63;
    int c0 = lane * 8;
    float acc[4][8];
    float4 b0 = *(const float4*)(bias + c0);
    float4 b1 = *(const float4*)(bias + c0 + 4);
    #pragma unroll
    for (int t = 0; t < 4; ++t) {
        acc[t][0]=b0.x; acc[t][1]=b0.y; acc[t][2]=b0.z; acc[t][3]=b0.w;
        acc[t][4]=b1.x; acc[t][5]=b1.y; acc[t][6]=b1.z; acc[t][7]=b1.w;
    }
    #pragma unroll 4
    for (int j = 0; j < 64; ++j) {
        float4 wa = *(const float4*)(W + (size_t)j*512 + c0);
        float4 wb = *(const float4*)(W + (size_t)j*512 + c0 + 4);
        #pragma unroll
        for (int t = 0; t < 4; ++t) {
            float a = xs[wv*4 + t][j];
            acc[t][0] += a*wa.x; acc[t][1] += a*wa.y; acc[t][2] += a*wa.z; acc[t][3] += a*wa.w;
            acc[t][4] += a*wb.x; acc[t][5] += a*wb.y; acc[t][6] += a*wb.z; acc[t][7] += a*wb.w;
        }
    }
    #pragma unroll
    for (int t = 0; t < 4; ++t) {
        int r = r0 + wv*4 + t;
        if (r < M) {
            float4 o0 = {acc[t][0],acc[t][1],acc[t][2],acc[t][3]};
            float4 o1 = {acc[t][4],acc[t][5],acc[t][6],acc[t][7]};
            *(float4*)(Y + (size_t)r*512 + c0)     = o0;
            *(float4*)(Y + (size_t)r*512 + c0 + 4) = o1;
        }
    }
}

// Per edge: e = ea@We + be (recompute), alpha[h] = scale * q[dst]·(k[src]+e); atomicMax m.
__global__ void __launch_bounds__(256) k_edge_alpha(
    const float* __restrict__ ea, const float* __restrict__ q, const float* __restrict__ k,
    const float* __restrict__ We, const float* __restrict__ be,
    const int* __restrict__ src, const int* __restrict__ dst,
    float* __restrict__ alpha, unsigned* __restrict__ mkey, int E)
{
    __shared__ __align__(16) float eas[16][64];
    int tid = threadIdx.x;
    int e0 = blockIdx.x * 16;
    for (int i = tid; i < 1024; i += 256) {
        int r = i >> 6, c = i & 63;
        int rr = e0 + r; if (rr >= E) rr = E - 1;
        eas[r][c] = ea[(size_t)rr * 64 + c];
    }
    __syncthreads();
    int wv = tid >> 6, lane = tid & 63;
    int c0 = lane * 8;
    int head = lane >> 3;
    float acc[4][8];
    float4 b0 = *(const float4*)(be + c0);
    float4 b1 = *(const float4*)(be + c0 + 4);
    #pragma unroll
    for (int t = 0; t < 4; ++t) {
        acc[t][0]=b0.x; acc[t][1]=b0.y; acc[t][2]=b0.z; acc[t][3]=b0.w;
        acc[t][4]=b1.x; acc[t][5]=b1.y; acc[t][6]=b1.z; acc[t][7]=b1.w;
    }
    #pragma unroll 4
    for (int j = 0; j < 64; ++j) {
        float4 wa = *(const float4*)(We + (size_t)j*512 + c0);
        float4 wb = *(const float4*)(We + (size_t)j*512 + c0 + 4);
        #pragma unroll
        for (int t = 0; t < 4; ++t) {
            float a = eas[wv*4 + t][j];
            acc[t][0] += a*wa.x; acc[t][1] += a*wa.y; acc[t][2] += a*wa.z; acc[t][3] += a*wa.w;
            acc[t][4] += a*wb.x; acc[t][5] += a*wb.y; acc[t][6] += a*wb.z; acc[t][7] += a*wb.w;
        }
    }
    #pragma unroll
    for (int t = 0; t < 4; ++t) {
        int e = e0 + wv*4 + t;
        if (e >= E) continue;
        int s = src[e], d = dst[e];
        const float* qp = q + (size_t)d*512 + c0;
        const float* kp = k + (size_t)s*512 + c0;
        float4 qa = *(const float4*)qp,      qb2 = *(const float4*)(qp + 4);
        float4 ka = *(const float4*)kp,      kb2 = *(const float4*)(kp + 4);
        float p = qa.x*(ka.x+acc[t][0]) + qa.y*(ka.y+acc[t][1])
                + qa.z*(ka.z+acc[t][2]) + qa.w*(ka.w+acc[t][3])
                + qb2.x*(kb2.x+acc[t][4]) + qb2.y*(kb2.y+acc[t][5])
                + qb2.z*(kb2.z+acc[t][6]) + qb2.w*(kb2.w+acc[t][7]);
        p += __shfl_xor(p, 1);
        p += __shfl_xor(p, 2);
        p += __shfl_xor(p, 4);
        p *= 0.125f; // 1/sqrt(64)
        if ((lane & 7) == 0) {
            alpha[(size_t)e*8 + head] = p;
            atomicMax(mkey + (size_t)d*8 + head, fkey(p));
        }
    }
}

// ex = exp(alpha - m[dst]); den += ex
__global__ void __launch_bounds__(256) k_softmax_ed(
    float* __restrict__ alpha, const unsigned* __restrict__ mkey,
    float* __restrict__ den, const int* __restrict__ dst, int E)
{
    int idx = blockIdx.x * 256 + threadIdx.x;
    if (idx >= E * 8) return;
    int e = idx >> 3, hh = idx & 7;
    int d = dst[e];
    float m = funkey(mkey[(size_t)d*8 + hh]);
    float ex = expf(alpha[idx] - m);
    alpha[idx] = ex;
    atomicAdd(den + (size_t)d*8 + hh, ex);
}

// Per edge: recompute e; a = ex/(den+1e-16)/HEADS; msg = a*(v[src]+e); atomicAdd into outmsg[dst]
__global__ void __launch_bounds__(256) k_edge_msg(
    const float* __restrict__ ea, const float* __restrict__ v,
    const float* __restrict__ We, const float* __restrict__ be,
    const float* __restrict__ ex, const float* __restrict__ den,
    const int* __restrict__ src, const int* __restrict__ dst,
    float* __restrict__ outmsg, int E)
{
    __shared__ __align__(16) float eas[16][64];
    int tid = threadIdx.x;
    int e0 = blockIdx.x * 16;
    for (int i = tid; i < 1024; i += 256) {
        int r = i >> 6, c = i & 63;
        int rr = e0 + r; if (rr >= E) rr = E - 1;
        eas[r][c] = ea[(size_t)rr * 64 + c];
    }
    __syncthreads();
    int wv = tid >> 6, lane = tid & 63;
    int c0 = lane * 8;
    int head = lane >> 3;
    float acc[4][8];
    float4 b0 = *(const float4*)(be + c0);
    float4 b1 = *(const float4*)(be + c0 + 4);
    #pragma unroll
    for (int t = 0; t < 4; ++t) {
        acc[t][0]=b0.x; acc[t][1]=b0.y; acc[t][2]=b0.z; acc[t][3]=b0.w;
        acc[t][4]=b1.x; acc[t][5]=b1.y; acc[t][6]=b1.z; acc[t][7]=b1.w;
    }
    #pragma unroll 4
    for (int j = 0; j < 64; ++j) {
        float4 wa = *(const float4*)(We + (size_t)j*512 + c0);
        float4 wb = *(const float4*)(We + (size_t)j*512 + c0 + 4);
        #pragma unroll
        for (int t = 0; t < 4; ++t) {
            float a = eas[wv*4 + t][j];
            acc[t][0] += a*wa.x; acc[t][1] += a*wa.y; acc[t][2] += a*wa.z; acc[t][3] += a*wa.w;
            acc[t][4] += a*wb.x; acc[t][5] += a*wb.y; acc[t][6] += a*wb.z; acc[t][7] += a*wb.w;
        }
    }
    #pragma unroll
    for (int t = 0; t < 4; ++t) {
        int e = e0 + wv*4 + t;
        if (e >= E) continue;
        int s = src[e], d = dst[e];
        float a = ex[(size_t)e*8 + head] / (den[(size_t)d*8 + head] + 1e-16f) * 0.125f;
        const float* vp = v + (size_t)s*512 + c0;
        float4 va = *(const float4*)vp, vb2 = *(const float4*)(vp + 4);
        float m[8];
        m[0] = a*(va.x + acc[t][0]); m[1] = a*(va.y + acc[t][1]);
        m[2] = a*(va.z + acc[t][2]); m[3] = a*(va.w + acc[t][3]);
        m[4] = a*(vb2.x + acc[t][4]); m[5] = a*(vb2.y + acc[t][5]);
        m[6] = a*(vb2.z + acc[t][6]); m[7] = a*(vb2.w + acc[t][7]);
        #pragma unroll
        for (int i = 0; i < 8; ++i) {
            m[i] += __shfl_xor(m[i], 8);
            m[i] += __shfl_xor(m[i], 16);
            m[i] += __shfl_xor(m[i], 32);
        }
        if (lane < 8) {
            float* op = outmsg + (size_t)d*64 + lane*8;
            #pragma unroll
            for (int i = 0; i < 8; ++i) atomicAdd(op + i, m[i]);
        }
    }
}

// h2 = relu(outmsg + h @ Ws + bs)   (64x64)
__global__ void __launch_bounds__(256) k_node_update(
    const float* __restrict__ h, const float* __restrict__ outmsg,
    const float* __restrict__ Ws, const float* __restrict__ bs,
    float* __restrict__ h2, int N)
{
    __shared__ __align__(16) float hs[32][64];
    int tid = threadIdx.x;
    int n0 = blockIdx.x * 32;
    for (int i = tid; i < 2048; i += 256) {
        int r = i >> 6, c = i & 63;
        int n = n0 + r;
        hs[r][c] = (n < N) ? h[(size_t)n*64 + c] : 0.f;
    }
    __syncthreads();
    int wv = tid >> 6, lane = tid & 63;
    float acc[8];
    #pragma unroll
    for (int t = 0; t < 8; ++t) acc[t] = 0.f;
    #pragma unroll 4
    for (int j = 0; j < 64; ++j) {
        float wval = Ws[(size_t)j*64 + lane];
        #pragma unroll
        for (int t = 0; t < 8; ++t) acc[t] += hs[wv*8 + t][j] * wval;
    }
    float bv = bs[lane];
    #pragma unroll
    for (int t = 0; t < 8; ++t) {
        int n = n0 + wv*8 + t;
        if (n < N) h2[(size_t)n*64 + lane] = fmaxf(acc[t] + bv + outmsg[(size_t)n*64 + lane], 0.f);
    }
}

// ea2 = relu([h[src], h[dst], ea] @ euW + eub)  (192x64)
__global__ void __launch_bounds__(256) k_edge_update(
    const float* __restrict__ h, const float* __restrict__ ea,
    const float* __restrict__ euW, const float* __restrict__ eub,
    const int* __restrict__ src, const int* __restrict__ dst,
    float* __restrict__ ea2, int E)
{
    __shared__ __align__(16) float s_src[32][64];
    __shared__ __align__(16) float s_dst[32][64];
    __shared__ __align__(16) float s_ea[32][64];
    __shared__ int sid[32], did[32];
    int tid = threadIdx.x;
    int e0 = blockIdx.x * 32;
    if (tid < 32) {
        int e = e0 + tid; if (e >= E) e = E - 1;
        sid[tid] = src[e]; did[tid] = dst[e];
    }
    __syncthreads();
    for (int i = tid; i < 2048; i += 256) {
        int r = i >> 6, c = i & 63;
        int e = e0 + r; if (e >= E) e = E - 1;
        s_src[r][c] = h[(size_t)sid[r]*64 + c];
        s_dst[r][c] = h[(size_t)did[r]*64 + c];
        s_ea[r][c]  = ea[(size_t)e*64 + c];
    }
    __syncthreads();
    int wv = tid >> 6, lane = tid & 63;
    float acc[8];
    float bv = eub[lane];
    #pragma unroll
    for (int t = 0; t < 8; ++t) acc[t] = bv;
    #pragma unroll 4
    for (int j = 0; j < 64; ++j) {
        float wval = euW[(size_t)j*64 + lane];
        #pragma unroll
        for (int t = 0; t < 8; ++t) acc[t] += s_src[wv*8 + t][j] * wval;
    }
    #pragma unroll 4
    for (int j = 0; j < 64; ++j) {
        float wval = euW[(size_t)(64 + j)*64 + lane];
        #pragma unroll
        for (int t = 0; t < 8; ++t) acc[t] += s_dst[wv*8 + t][j] * wval;
    }
    #pragma unroll 4
    for (int j = 0; j < 64; ++j) {
        float wval = euW[(size_t)(128 + j)*64 + lane];
        #pragma unroll
        for (int t = 0; t < 8; ++t) acc[t] += s_ea[wv*8 + t][j] * wval;
    }
    #pragma unroll
    for (int t = 0; t < 8; ++t) {
        int e = e0 + wv*8 + t;
        if (e < E) ea2[(size_t)e*64 + lane] = fmaxf(acc[t], 0.f);
    }
}

// Node pooling: batch is sorted -> run-length accumulate, flush on graph change.
__global__ void __launch_bounds__(64) k_node_pool(
    const float* __restrict__ h, const int* __restrict__ batch,
    float* __restrict__ npool, float* __restrict__ cn, int N)
{
    int lane = threadIdx.x;
    int n0 = blockIdx.x * 64;
    float acc = 0.f; int cur = -1; int run = 0;
    for (int i = 0; i < 64; ++i) {
        int n = n0 + i;
        if (n >= N) break;
        int b = batch[n];
        if (b != cur) {
            if (cur >= 0) {
                atomicAdd(npool + (size_t)cur*64 + lane, acc);
                if (lane == 0) atomicAdd(cn + cur, (float)run);
            }
            cur = b; acc = 0.f; run = 0;
        }
        acc += h[(size_t)n*64 + lane];
        ++run;
    }
    if (cur >= 0) {
        atomicAdd(npool + (size_t)cur*64 + lane, acc);
        if (lane == 0) atomicAdd(cn + cur, (float)run);
    }
}

// Edge pooling via LDS histogram (batch[src] is random order)
__global__ void __launch_bounds__(256) k_edge_pool(
    const float* __restrict__ ea, const int* __restrict__ src, const int* __restrict__ batch,
    float* __restrict__ epool, float* __restrict__ ce, int E)
{
    __shared__ float pool_s[32][64];
    __shared__ float cnt_s[32];
    int tid = threadIdx.x;
    for (int i = tid; i < 2048; i += 256) ((float*)pool_s)[i] = 0.f;
    if (tid < 32) cnt_s[tid] = 0.f;
    __syncthreads();
    int wv = tid >> 6, lane = tid & 63;
    int base = blockIdx.x * 256 + wv * 64;
    #pragma unroll 4
    for (int i = 0; i < 64; ++i) {
        int e = base + i;
        if (e < E) {
            int b = batch[src[e]];
            float val = ea[(size_t)e*64 + lane];
            atomicAdd(&pool_s[b][lane], val);
            if (lane == 0) atomicAdd(&cnt_s[b], 1.f);
        }
    }
    __syncthreads();
    for (int i = tid; i < 2048; i += 256) atomicAdd(epool + i, ((float*)pool_s)[i]);
    if (tid < 32) atomicAdd(ce + tid, cnt_s[tid]);
}

// Final head MLP per graph: g=[npool/cn, epool/ce] -> relu(128x64) -> relu(64x64) -> tanh(64x2)
__global__ void __launch_bounds__(64) k_head_mlp(
    const float* __restrict__ npool, const float* __restrict__ epool,
    const float* __restrict__ cn, const float* __restrict__ ce,
    const float* __restrict__ rW1, const float* __restrict__ rb1,
    const float* __restrict__ rW2, const float* __restrict__ rb2,
    const float* __restrict__ rW3, const float* __restrict__ rb3,
    float* __restrict__ out)
{
    __shared__ float g[128];
    __shared__ float h1[64];
    __shared__ float h2[64];
    int b = blockIdx.x, lane = threadIdx.x;
    float cnv = fmaxf(cn[b], 1.f), cev = fmaxf(ce[b], 1.f);
    g[lane]      = npool[(size_t)b*64 + lane] / cnv;
    g[64 + lane] = epool[(size_t)b*64 + lane] / cev;
    __syncthreads();
    float acc = rb1[lane];
    #pragma unroll 4
    for (int j = 0; j < 128; ++j) acc += g[j] * rW1[j*64 + lane];
    h1[lane] = fmaxf(acc, 0.f);
    __syncthreads();
    acc = rb2[lane];
    #pragma unroll 4
    for (int j = 0; j < 64; ++j) acc += h1[j] * rW2[j*64 + lane];
    h2[lane] = fmaxf(acc, 0.f);
    __syncthreads();
    if (lane < 2) {
        float o = rb3[lane];
        for (int j = 0; j < 64; ++j) o += h2[j] * rW3[j*2 + lane];
        out[b*2 + lane] = tanhf(o);
    }
}

extern "C" void kernel_launch(void* const* d_in, const int* in_sizes, int n_in,
                              void* d_out, int out_size, void* d_ws, size_t ws_size,
                              hipStream_t stream)
{
    const float* x         = (const float*)d_in[0];
    const float* edge_attr = (const float*)d_in[1];
    const float* means     = (const float*)d_in[2];
    const float* log_stds  = (const float*)d_in[3];
    const float* spW       = (const float*)d_in[4];
    const float* spb       = (const float*)d_in[5];
    const float* neW       = (const float*)d_in[6];
    const float* neb       = (const float*)d_in[7];
    const float* eeW       = (const float*)d_in[8];
    const float* eeb       = (const float*)d_in[9];
    const float* Wq        = (const float*)d_in[10];
    const float* bq        = (const float*)d_in[11];
    const float* Wk        = (const float*)d_in[12];
    const float* bk        = (const float*)d_in[13];
    const float* Wv        = (const float*)d_in[14];
    const float* bv        = (const float*)d_in[15];
    const float* We        = (const float*)d_in[16];
    const float* be        = (const float*)d_in[17];
    const float* Ws        = (const float*)d_in[18];
    const float* bs        = (const float*)d_in[19];
    const float* euW       = (const float*)d_in[20];
    const float* eub       = (const float*)d_in[21];
    const float* rW1       = (const float*)d_in[22];
    const float* rb1       = (const float*)d_in[23];
    const float* rW2       = (const float*)d_in[24];
    const float* rb2       = (const float*)d_in[25];
    const float* rW3       = (const float*)d_in[26];
    const float* rb3       = (const float*)d_in[27];
    const int* eidx        = (const int*)d_in[28];
    const int* batch       = (const int*)d_in[29];

    int N = in_sizes[0] / 7;
    int E = in_sizes[1] / 4;
    const int G = 32; // num_graphs (fixed by setup_inputs)
    const int* srcp = eidx;
    const int* dstp = eidx + E;

    float* ws = (float*)d_ws;
    size_t off = 0;
    float* hA     = ws + off; off += (size_t)N * 64;
    float* hB     = ws + off; off += (size_t)N * 64;
    float* eaA    = ws + off; off += (size_t)E * 64;
    float* eaB    = ws + off; off += (size_t)E * 64;
    float* qb_    = ws + off; off += (size_t)N * 512;
    float* kb_    = ws + off; off += (size_t)N * 512;
    float* vb_    = ws + off; off += (size_t)N * 512;
    float* alpha  = ws + off; off += (size_t)E * 8;
    unsigned* mkey = (unsigned*)(ws + off); off += (size_t)N * 8;   // contiguous with den+outmsg
    float* den    = ws + off; off += (size_t)N * 8;
    float* outmsg = ws + off; off += (size_t)N * 64;
    float* npool  = ws + off; off += (size_t)G * 64;
    float* epool  = ws + off; off += (size_t)G * 64;
    float* cn     = ws + off; off += G;
    float* ce     = ws + off; off += G;

    // zero pool accumulators (npool..ce contiguous)
    hipMemsetAsync(npool, 0, (size_t)(G * 130) * sizeof(float), stream);

    k_node_embed<<<(N * 64 + 255) / 256, 256, 0, stream>>>(x, neW, neb, hA, N);
    k_edge_init<<<(E + 3) / 4, 256, 0, stream>>>(x, edge_attr, means, log_stds,
                                                 spW, spb, eeW, eeb, srcp, dstp, eaA, E);

    float* hcur = hA;  float* hnext = hB;
    float* eacur = eaA; float* eanext = eaB;
    for (int l = 0; l < 3; ++l) {
        const float* Wq_l = Wq + (size_t)l * 64 * 512;
        const float* Wk_l = Wk + (size_t)l * 64 * 512;
        const float* Wv_l = Wv + (size_t)l * 64 * 512;
        const float* We_l = We + (size_t)l * 64 * 512;
        k_gemm512<<<(N + 15) / 16, 256, 0, stream>>>(hcur, Wq_l, bq + (size_t)l * 512, qb_, N);
        k_gemm512<<<(N + 15) / 16, 256, 0, stream>>>(hcur, Wk_l, bk + (size_t)l * 512, kb_, N);
        k_gemm512<<<(N + 15) / 16, 256, 0, stream>>>(hcur, Wv_l, bv + (size_t)l * 512, vb_, N);
        // zero mkey|den|outmsg (contiguous N*80 floats)
        hipMemsetAsync(mkey, 0, (size_t)N * 80 * sizeof(float), stream);
        k_edge_alpha<<<(E + 15) / 16, 256, 0, stream>>>(eacur, qb_, kb_, We_l, be + (size_t)l * 512,
                                                        srcp, dstp, alpha, mkey, E);
        k_softmax_ed<<<(E * 8 + 255) / 256, 256, 0, stream>>>(alpha, mkey, den, dstp, E);
        k_edge_msg<<<(E + 15) / 16, 256, 0, stream>>>(eacur, vb_, We_l, be + (size_t)l * 512,
                                                      alpha, den, srcp, dstp, outmsg, E);
        k_node_update<<<(N + 31) / 32, 256, 0, stream>>>(hcur, outmsg, Ws + (size_t)l * 64 * 64,
                                                         bs + (size_t)l * 64, hnext, N);
        k_edge_update<<<(E + 31) / 32, 256, 0, stream>>>(hnext, eacur, euW + (size_t)l * 192 * 64,
                                                         eub + (size_t)l * 64, srcp, dstp, eanext, E);
        float* t1 = hcur; hcur = hnext; hnext = t1;
        float* t2 = eacur; eacur = eanext; eanext = t2;
    }

    k_node_pool<<<(N + 63) / 64, 64, 0, stream>>>(hcur, batch, npool, cn, N);
    k_edge_pool<<<(E + 255) / 256, 256, 0, stream>>>(eacur, srcp, batch, epool, ce, E);
    k_head_mlp<<<G, 64, 0, stream>>>(npool, epool, cn, ce, rW1, rb1, rW2, rb2, rW3, rb3,
                                     (float*)d_out);
}

// Round 2
// 2051.287 us; speedup vs baseline: 1.0000x; 1.0000x over previous
//
#include <hip/hip_runtime.h>
#include <hip/hip_bf16.h>
#include <cstdint>
#include <cstddef>

// N=20000, E=100000, G=32, HID=64, HEADS=8, HC=64, HO=512, L=3, K=4. All fp32.
// New path: eproj materialized once/layer (GEMM w/ alpha epilogue), CSR-by-dst
// fused softmax+aggregate (no atomics). Fallback to round-1 path if ws too small.

__device__ __forceinline__ unsigned fkey(float f) {
    unsigned u = __float_as_uint(f);
    return (u & 0x80000000u) ? ~u : (u | 0x80000000u);
}
__device__ __forceinline__ float funkey(unsigned kk) {
    unsigned u = (kk & 0x80000000u) ? (kk & 0x7FFFFFFFu) : ~kk;
    return __uint_as_float(u);
}

// ---------------- shared kernels (both paths) ----------------

__global__ void __launch_bounds__(256) k_node_embed(
    const float* __restrict__ x, const float* __restrict__ neW, const float* __restrict__ neb,
    float* __restrict__ h, int N)
{
    int idx = blockIdx.x * 256 + threadIdx.x;
    int n = idx >> 6, c = idx & 63;
    if (n >= N) return;
    float acc = neb[c];
    #pragma unroll
    for (int j = 0; j < 7; ++j) acc += x[(size_t)n * 7 + j] * neW[j * 64 + c];
    h[(size_t)n * 64 + c] = fmaxf(acc, 0.f);
}

__global__ void __launch_bounds__(256) k_edge_init(
    const float* __restrict__ x, const float* __restrict__ edge_attr,
    const float* __restrict__ means, const float* __restrict__ log_stds,
    const float* __restrict__ spW, const float* __restrict__ spb,
    const float* __restrict__ eeW, const float* __restrict__ eeb,
    const int* __restrict__ src, const int* __restrict__ dst,
    float* __restrict__ ea, int E)
{
    int gw = (blockIdx.x * 256 + threadIdx.x) >> 6;
    int lane = threadIdx.x & 63;
    if (gw >= E) return;
    int s = src[gw], d = dst[gw];
    const float* ps = x + (size_t)s * 7;
    const float* pd = x + (size_t)d * 7;
    float slx = ps[0], sly = ps[1], srx = ps[2], sry = ps[3];
    float dlx = pd[0], dly = pd[1], drx = pd[2], dry = pd[3];
    float u[8];
    float rx, ry;
    rx = dlx - slx; ry = dly - sly; u[0] = sqrtf(rx*rx + ry*ry); u[1] = atan2f(ry, rx);
    rx = dlx - srx; ry = dly - sry; u[2] = sqrtf(rx*rx + ry*ry); u[3] = atan2f(ry, rx);
    rx = drx - slx; ry = dry - sly; u[4] = sqrtf(rx*rx + ry*ry); u[5] = atan2f(ry, rx);
    rx = drx - srx; ry = dry - sry; u[6] = sqrtf(rx*rx + ry*ry); u[7] = atan2f(ry, rx);
    float w[4];
    #pragma unroll
    for (int kk = 0; kk < 4; ++kk) {
        float ssum = 0.f;
        #pragma unroll
        for (int dd = 0; dd < 8; ++dd) {
            float stdv = expf(log_stds[kk*8+dd]) + 1e-6f;
            float z = (u[dd] - means[kk*8+dd]) / stdv;
            ssum += z * z;
        }
        w[kk] = expf(-0.5f * ssum);
    }
    float accs = spb[lane];
    #pragma unroll
    for (int kk = 0; kk < 4; ++kk) accs += w[kk] * spW[kk*64 + lane];
    float acce = eeb[lane];
    #pragma unroll
    for (int j = 0; j < 4; ++j) acce += edge_attr[(size_t)gw*4 + j] * eeW[j*64 + lane];
    ea[(size_t)gw*64 + lane] = fmaxf(acce, 0.f) + fmaxf(accs, 0.f);
}

__global__ void __launch_bounds__(256) k_node_update(
    const float* __restrict__ h, const float* __restrict__ outmsg,
    const float* __restrict__ Ws, const float* __restrict__ bs,
    float* __restrict__ h2, int N)
{
    __shared__ __align__(16) float hs[32][64];
    int tid = threadIdx.x;
    int n0 = blockIdx.x * 32;
    for (int i = tid; i < 2048; i += 256) {
        int r = i >> 6, c = i & 63;
        int n = n0 + r;
        hs[r][c] = (n < N) ? h[(size_t)n*64 + c] : 0.f;
    }
    __syncthreads();
    int wv = tid >> 6, lane = tid & 63;
    float acc[8];
    #pragma unroll
    for (int t = 0; t < 8; ++t) acc[t] = 0.f;
    #pragma unroll 4
    for (int j = 0; j < 64; ++j) {
        float wval = Ws[(size_t)j*64 + lane];
        #pragma unroll
        for (int t = 0; t < 8; ++t) acc[t] += hs[wv*8 + t][j] * wval;
    }
    float bv = bs[lane];
    #pragma unroll
    for (int t = 0; t < 8; ++t) {
        int n = n0 + wv*8 + t;
        if (n < N) h2[(size_t)n*64 + lane] = fmaxf(acc[t] + bv + outmsg[(size_t)n*64 + lane], 0.f);
    }
}

__global__ void __launch_bounds__(256) k_edge_update(
    const float* __restrict__ h, const float* __restrict__ ea,
    const float* __restrict__ euW, const float* __restrict__ eub,
    const int* __restrict__ src, const int* __restrict__ dst,
    float* __restrict__ ea2, int E)
{
    __shared__ __align__(16) float s_src[32][64];
    __shared__ __align__(16) float s_dst[32][64];
    __shared__ __align__(16) float s_ea[32][64];
    __shared__ int sid[32], did[32];
    int tid = threadIdx.x;
    int e0 = blockIdx.x * 32;
    if (tid < 32) {
        int e = e0 + tid; if (e >= E) e = E - 1;
        sid[tid] = src[e]; did[tid] = dst[e];
    }
    __syncthreads();
    for (int i = tid; i < 2048; i += 256) {
        int r = i >> 6, c = i & 63;
        int e = e0 + r; if (e >= E) e = E - 1;
        s_src[r][c] = h[(size_t)sid[r]*64 + c];
        s_dst[r][c] = h[(size_t)did[r]*64 + c];
        s_ea[r][c]  = ea[(size_t)e*64 + c];
    }
    __syncthreads();
    int wv = tid >> 6, lane = tid & 63;
    float acc[8];
    float bv = eub[lane];
    #pragma unroll
    for (int t = 0; t < 8; ++t) acc[t] = bv;
    #pragma unroll 4
    for (int j = 0; j < 64; ++j) {
        float wval = euW[(size_t)j*64 + lane];
        #pragma unroll
        for (int t = 0; t < 8; ++t) acc[t] += s_src[wv*8 + t][j] * wval;
    }
    #pragma unroll 4
    for (int j = 0; j < 64; ++j) {
        float wval = euW[(size_t)(64 + j)*64 + lane];
        #pragma unroll
        for (int t = 0; t < 8; ++t) acc[t] += s_dst[wv*8 + t][j] * wval;
    }
    #pragma unroll 4
    for (int j = 0; j < 64; ++j) {
        float wval = euW[(size_t)(128 + j)*64 + lane];
        #pragma unroll
        for (int t = 0; t < 8; ++t) acc[t] += s_ea[wv*8 + t][j] * wval;
    }
    #pragma unroll
    for (int t = 0; t < 8; ++t) {
        int e = e0 + wv*8 + t;
        if (e < E) ea2[(size_t)e*64 + lane] = fmaxf(acc[t], 0.f);
    }
}

__global__ void __launch_bounds__(64) k_node_pool(
    const float* __restrict__ h, const int* __restrict__ batch,
    float* __restrict__ npool, float* __restrict__ cn, int N)
{
    int lane = threadIdx.x;
    int n0 = blockIdx.x * 64;
    float acc = 0.f; int cur = -1; int run = 0;
    for (int i = 0; i < 64; ++i) {
        int n = n0 + i;
        if (n >= N) break;
        int b = batch[n];
        if (b != cur) {
            if (cur >= 0) {
                atomicAdd(npool + (size_t)cur*64 + lane, acc);
                if (lane == 0) atomicAdd(cn + cur, (float)run);
            }
            cur = b; acc = 0.f; run = 0;
        }
        acc += h[(size_t)n*64 + lane];
        ++run;
    }
    if (cur >= 0) {
        atomicAdd(npool + (size_t)cur*64 + lane, acc);
        if (lane == 0) atomicAdd(cn + cur, (float)run);
    }
}

__global__ void __launch_bounds__(256) k_edge_pool(
    const float* __restrict__ ea, const int* __restrict__ src, const int* __restrict__ batch,
    float* __restrict__ epool, float* __restrict__ ce, int E)
{
    __shared__ float pool_s[32][64];
    __shared__ float cnt_s[32];
    int tid = threadIdx.x;
    for (int i = tid; i < 2048; i += 256) ((float*)pool_s)[i] = 0.f;
    if (tid < 32) cnt_s[tid] = 0.f;
    __syncthreads();
    int wv = tid >> 6, lane = tid & 63;
    int base = blockIdx.x * 256 + wv * 64;
    #pragma unroll 4
    for (int i = 0; i < 64; ++i) {
        int e = base + i;
        if (e < E) {
            int b = batch[src[e]];
            float val = ea[(size_t)e*64 + lane];
            atomicAdd(&pool_s[b][lane], val);
            if (lane == 0) atomicAdd(&cnt_s[b], 1.f);
        }
    }
    __syncthreads();
    for (int i = tid; i < 2048; i += 256) atomicAdd(epool + i, ((float*)pool_s)[i]);
    if (tid < 32) atomicAdd(ce + tid, cnt_s[tid]);
}

__global__ void __launch_bounds__(64) k_head_mlp(
    const float* __restrict__ npool, const float* __restrict__ epool,
    const float* __restrict__ cn, const float* __restrict__ ce,
    const float* __restrict__ rW1, const float* __restrict__ rb1,
    const float* __restrict__ rW2, const float* __restrict__ rb2,
    const float* __restrict__ rW3, const float* __restrict__ rb3,
    float* __restrict__ out)
{
    __shared__ float g[128];
    __shared__ float h1[64];
    __shared__ float h2[64];
    int b = blockIdx.x, lane = threadIdx.x;
    float cnv = fmaxf(cn[b], 1.f), cev = fmaxf(ce[b], 1.f);
    g[lane]      = npool[(size_t)b*64 + lane] / cnv;
    g[64 + lane] = epool[(size_t)b*64 + lane] / cev;
    __syncthreads();
    float acc = rb1[lane];
    #pragma unroll 4
    for (int j = 0; j < 128; ++j) acc += g[j] * rW1[j*64 + lane];
    h1[lane] = fmaxf(acc, 0.f);
    __syncthreads();
    acc = rb2[lane];
    #pragma unroll 4
    for (int j = 0; j < 64; ++j) acc += h1[j] * rW2[j*64 + lane];
    h2[lane] = fmaxf(acc, 0.f);
    __syncthreads();
    if (lane < 2) {
        float o = rb3[lane];
        for (int j = 0; j < 64; ++j) o += h2[j] * rW3[j*2 + lane];
        out[b*2 + lane] = tanhf(o);
    }
}

// ---------------- NEW PATH kernels ----------------

// Y = X @ W + bias  (X: M x 64, W: 64 x 512). BM=32, wave=8 rows, lane=8 cols.
__global__ void __launch_bounds__(256) k_gemm512_r32(
    const float* __restrict__ X, const float* __restrict__ W, const float* __restrict__ bias,
    float* __restrict__ Y, int M)
{
    __shared__ __align__(16) float xs[32][64];
    int tid = threadIdx.x;
    int r0 = blockIdx.x * 32;
    for (int i = tid; i < 2048; i += 256) {
        int r = i >> 6, c = i & 63;
        int rr = r0 + r;
        xs[r][c] = (rr < M) ? X[(size_t)rr * 64 + c] : 0.f;
    }
    __syncthreads();
    int wv = tid >> 6, lane = tid & 63;
    int c0 = lane * 8;
    float acc[8][8];
    float4 b0 = *(const float4*)(bias + c0);
    float4 b1 = *(const float4*)(bias + c0 + 4);
    #pragma unroll
    for (int t = 0; t < 8; ++t) {
        acc[t][0]=b0.x; acc[t][1]=b0.y; acc[t][2]=b0.z; acc[t][3]=b0.w;
        acc[t][4]=b1.x; acc[t][5]=b1.y; acc[t][6]=b1.z; acc[t][7]=b1.w;
    }
    #pragma unroll 2
    for (int j = 0; j < 64; ++j) {
        float4 wa = *(const float4*)(W + (size_t)j*512 + c0);
        float4 wb = *(const float4*)(W + (size_t)j*512 + c0 + 4);
        #pragma unroll
        for (int t = 0; t < 8; ++t) {
            float a = xs[wv*8 + t][j];
            acc[t][0] += a*wa.x; acc[t][1] += a*wa.y; acc[t][2] += a*wa.z; acc[t][3] += a*wa.w;
            acc[t][4] += a*wb.x; acc[t][5] += a*wb.y; acc[t][6] += a*wb.z; acc[t][7] += a*wb.w;
        }
    }
    #pragma unroll
    for (int t = 0; t < 8; ++t) {
        int r = r0 + wv*8 + t;
        if (r < M) {
            float4 o0 = {acc[t][0],acc[t][1],acc[t][2],acc[t][3]};
            float4 o1 = {acc[t][4],acc[t][5],acc[t][6],acc[t][7]};
            *(float4*)(Y + (size_t)r*512 + c0)     = o0;
            *(float4*)(Y + (size_t)r*512 + c0 + 4) = o1;
        }
    }
}

// eproj = ea @ We + be (stored), alpha[e][h] = 0.125 * q[dst]·(k[src]+e) (raw, pre-exp)
__global__ void __launch_bounds__(256) k_gemm_e(
    const float* __restrict__ ea, const float* __restrict__ We, const float* __restrict__ be,
    const float* __restrict__ q, const float* __restrict__ k,
    const int* __restrict__ src, const int* __restrict__ dst,
    float* __restrict__ eproj, float* __restrict__ alpha, int E)
{
    __shared__ __align__(16) float eas[32][64];
    int tid = threadIdx.x;
    int e0 = blockIdx.x * 32;
    for (int i = tid; i < 2048; i += 256) {
        int r = i >> 6, c = i & 63;
        int rr = e0 + r; if (rr >= E) rr = E - 1;
        eas[r][c] = ea[(size_t)rr * 64 + c];
    }
    __syncthreads();
    int wv = tid >> 6, lane = tid & 63;
    int c0 = lane * 8;
    int head = lane >> 3;
    float acc[8][8];
    float4 b0 = *(const float4*)(be + c0);
    float4 b1 = *(const float4*)(be + c0 + 4);
    #pragma unroll
    for (int t = 0; t < 8; ++t) {
        acc[t][0]=b0.x; acc[t][1]=b0.y; acc[t][2]=b0.z; acc[t][3]=b0.w;
        acc[t][4]=b1.x; acc[t][5]=b1.y; acc[t][6]=b1.z; acc[t][7]=b1.w;
    }
    #pragma unroll 2
    for (int j = 0; j < 64; ++j) {
        float4 wa = *(const float4*)(We + (size_t)j*512 + c0);
        float4 wb = *(const float4*)(We + (size_t)j*512 + c0 + 4);
        #pragma unroll
        for (int t = 0; t < 8; ++t) {
            float a = eas[wv*8 + t][j];
            acc[t][0] += a*wa.x; acc[t][1] += a*wa.y; acc[t][2] += a*wa.z; acc[t][3] += a*wa.w;
            acc[t][4] += a*wb.x; acc[t][5] += a*wb.y; acc[t][6] += a*wb.z; acc[t][7] += a*wb.w;
        }
    }
    #pragma unroll
    for (int t = 0; t < 8; ++t) {
        int e = e0 + wv*8 + t;
        if (e >= E) continue;
        float4 o0 = {acc[t][0],acc[t][1],acc[t][2],acc[t][3]};
        float4 o1 = {acc[t][4],acc[t][5],acc[t][6],acc[t][7]};
        *(float4*)(eproj + (size_t)e*512 + c0)     = o0;
        *(float4*)(eproj + (size_t)e*512 + c0 + 4) = o1;
        int s = src[e], d = dst[e];
        const float* qp = q + (size_t)d*512 + c0;
        const float* kp = k + (size_t)s*512 + c0;
        float4 qa = *(const float4*)qp, qb2 = *(const float4*)(qp + 4);
        float4 ka = *(const float4*)kp, kb2 = *(const float4*)(kp + 4);
        float p = qa.x*(ka.x+acc[t][0]) + qa.y*(ka.y+acc[t][1])
                + qa.z*(ka.z+acc[t][2]) + qa.w*(ka.w+acc[t][3])
                + qb2.x*(kb2.x+acc[t][4]) + qb2.y*(kb2.y+acc[t][5])
                + qb2.z*(kb2.z+acc[t][6]) + qb2.w*(kb2.w+acc[t][7]);
        p += __shfl_xor(p, 1);
        p += __shfl_xor(p, 2);
        p += __shfl_xor(p, 4);
        p *= 0.125f; // 1/sqrt(HC)
        if ((lane & 7) == 0) alpha[(size_t)e*8 + head] = p;
    }
}

// CSR build: histogram, 1-block scan, scatter
__global__ void __launch_bounds__(256) k_hist(
    const int* __restrict__ dst, int* __restrict__ deg, int E)
{
    int e = blockIdx.x * 256 + threadIdx.x;
    if (e < E) atomicAdd(deg + dst[e], 1);
}

__global__ void __launch_bounds__(1024) k_scan(
    const int* __restrict__ deg, int* __restrict__ ptr, int* __restrict__ headw, int N)
{
    __shared__ int part[1024];
    int t = threadIdx.x;
    int per = (N + 1023) / 1024;
    int s = 0;
    for (int i = 0; i < per; ++i) { int idx = t*per + i; if (idx < N) s += deg[idx]; }
    part[t] = s;
    __syncthreads();
    for (int off = 1; off < 1024; off <<= 1) {
        int v = (t >= off) ? part[t - off] : 0;
        __syncthreads();
        part[t] += v;
        __syncthreads();
    }
    int base = (t > 0) ? part[t - 1] : 0;
    for (int i = 0; i < per; ++i) {
        int idx = t*per + i;
        if (idx < N) { ptr[idx] = base; headw[idx] = base; base += deg[idx]; }
    }
    if (t == 1023) ptr[N] = part[1023];
}

__global__ void __launch_bounds__(256) k_scatter(
    const int* __restrict__ dst, int* __restrict__ headw, int* __restrict__ perm, int E)
{
    int e = blockIdx.x * 256 + threadIdx.x;
    if (e < E) {
        int pos = atomicAdd(headw + dst[e], 1);
        perm[pos] = e;
    }
}

// Fused per-dst softmax + aggregation. Wave per node (4 nodes/block). No atomics.
__global__ void __launch_bounds__(256) k_attn_node(
    const float* __restrict__ alpha, const float* __restrict__ eproj,
    const float* __restrict__ vbuf, const int* __restrict__ ptr,
    const int* __restrict__ perm, const int* __restrict__ srcp,
    float* __restrict__ outmsg, int N)
{
    int wv = threadIdx.x >> 6, lane = threadIdx.x & 63;
    int n = blockIdx.x * 4 + wv;
    if (n >= N) return;
    int b = ptr[n], e_ = ptr[n + 1];
    // pass 1: per-head max & denom. lane = i*8 + h
    int h = lane & 7, i = lane >> 3;
    float m = -3.4e38f;
    for (int j = b + i; j < e_; j += 8) {
        int e = perm[j];
        m = fmaxf(m, alpha[(size_t)e*8 + h]);
    }
    m = fmaxf(m, __shfl_xor(m, 8));
    m = fmaxf(m, __shfl_xor(m, 16));
    m = fmaxf(m, __shfl_xor(m, 32));
    float s = 0.f;
    for (int j = b + i; j < e_; j += 8) {
        int e = perm[j];
        s += expf(alpha[(size_t)e*8 + h] - m);
    }
    s += __shfl_xor(s, 8);
    s += __shfl_xor(s, 16);
    s += __shfl_xor(s, 32);
    // redistribute to col-mapping: lane owns cols lane*8.., head = lane>>3
    int head = lane >> 3;
    float mh = __shfl(m, head);   // lane 'head' holds stats for h=head
    float sh = __shfl(s, head);
    float inv = 0.125f / (sh + 1e-16f);   // includes 1/HEADS
    // pass 2: weighted aggregation
    int c0 = lane * 8;
    float acc[8];
    #pragma unroll
    for (int t = 0; t < 8; ++t) acc[t] = 0.f;
    for (int j = b; j < e_; ++j) {
        int e = perm[j];
        float av = expf(alpha[(size_t)e*8 + head] - mh) * inv;
        int si = srcp[e];
        const float* ep = eproj + (size_t)e*512 + c0;
        const float* vp = vbuf + (size_t)si*512 + c0;
        float4 ea4 = *(const float4*)ep, eb4 = *(const float4*)(ep + 4);
        float4 va4 = *(const float4*)vp, vb4 = *(const float4*)(vp + 4);
        acc[0] += av*(va4.x + ea4.x); acc[1] += av*(va4.y + ea4.y);
        acc[2] += av*(va4.z + ea4.z); acc[3] += av*(va4.w + ea4.w);
        acc[4] += av*(vb4.x + eb4.x); acc[5] += av*(vb4.y + eb4.y);
        acc[6] += av*(vb4.z + eb4.z); acc[7] += av*(vb4.w + eb4.w);
    }
    #pragma unroll
    for (int t = 0; t < 8; ++t) {
        acc[t] += __shfl_xor(acc[t], 8);
        acc[t] += __shfl_xor(acc[t], 16);
        acc[t] += __shfl_xor(acc[t], 32);
    }
    if (lane < 8) {
        float4 o0 = {acc[0], acc[1], acc[2], acc[3]};
        float4 o1 = {acc[4], acc[5], acc[6], acc[7]};
        *(float4*)(outmsg + (size_t)n*64 + lane*8)     = o0;
        *(float4*)(outmsg + (size_t)n*64 + lane*8 + 4) = o1;
    }
}

// ---------------- OLD PATH kernels (fallback) ----------------

__global__ void __launch_bounds__(256) k_gemm512(
    const float* __restrict__ X, const float* __restrict__ W, const float* __restrict__ bias,
    float* __restrict__ Y, int M)
{
    __shared__ __align__(16) float xs[16][64];
    int tid = threadIdx.x;
    int r0 = blockIdx.x * 16;
    for (int i = tid; i < 1024; i += 256) {
        int r = i >> 6, c = i & 63;
        int rr = r0 + r;
        xs[r][c] = (rr < M) ? X[(size_t)rr * 64 + c] : 0.f;
    }
    __syncthreads();
    int wv = tid >> 6, lane = tid & 63;
    int c0 = lane * 8;
    float acc[4][8];
    float4 b0 = *(const float4*)(bias + c0);
    float4 b1 = *(const float4*)(bias + c0 + 4);
    #pragma unroll
    for (int t = 0; t < 4; ++t) {
        acc[t][0]=b0.x; acc[t][1]=b0.y; acc[t][2]=b0.z; acc[t][3]=b0.w;
        acc[t][4]=b1.x; acc[t][5]=b1.y; acc[t][6]=b1.z; acc[t][7]=b1.w;
    }
    #pragma unroll 4
    for (int j = 0; j < 64; ++j) {
        float4 wa = *(const float4*)(W + (size_t)j*512 + c0);
        float4 wb = *(const float4*)(W + (size_t)j*512 + c0 + 4);
        #pragma unroll
        for (int t = 0; t < 4; ++t) {
            float a = xs[wv*4 + t][j];
            acc[t][0] += a*wa.x; acc[t][1] += a*wa.y; acc[t][2] += a*wa.z; acc[t][3] += a*wa.w;
            acc[t][4] += a*wb.x; acc[t][5] += a*wb.y; acc[t][6] += a*wb.z; acc[t][7] += a*wb.w;
        }
    }
    #pragma unroll
    for (int t = 0; t < 4; ++t) {
        int r = r0 + wv*4 + t;
        if (r < M) {
            float4 o0 = {acc[t][0],acc[t][1],acc[t][2],acc[t][3]};
            float4 o1 = {acc[t][4],acc[t][5],acc[t][6],acc[t][7]};
            *(float4*)(Y + (size_t)r*512 + c0)     = o0;
            *(float4*)(Y + (size_t)r*512 + c0 + 4) = o1;
        }
    }
}

__global__ void __launch_bounds__(256) k_edge_alpha(
    const float* __restrict__ ea, const float* __restrict__ q, const float* __restrict__ k,
    const float* __restrict__ We, const float* __restrict__ be,
    const int* __restrict__ src, const int* __restrict__ dst,
    float* __restrict__ alpha, unsigned* __restrict__ mkey, int E)
{
    __shared__ __align__(16) float eas[16][64];
    int tid = threadIdx.x;
    int e0 = blockIdx.x * 16;
    for (int i = tid; i < 1024; i += 256) {
        int r = i >> 6, c = i & 63;
        int rr = e0 + r; if (rr >= E) rr = E - 1;
        eas[r][c] = ea[(size_t)rr * 64 + c];
    }
    __syncthreads();
    int wv = tid >> 6, lane = tid & 63;
    int c0 = lane * 8;
    int head = lane >> 3;
    float acc[4][8];
    float4 b0 = *(const float4*)(be + c0);
    float4 b1 = *(const float4*)(be + c0 + 4);
    #pragma unroll
    for (int t = 0; t < 4; ++t) {
        acc[t][0]=b0.x; acc[t][1]=b0.y; acc[t][2]=b0.z; acc[t][3]=b0.w;
        acc[t][4]=b1.x; acc[t][5]=b1.y; acc[t][6]=b1.z; acc[t][7]=b1.w;
    }
    #pragma unroll 4
    for (int j = 0; j < 64; ++j) {
        float4 wa = *(const float4*)(We + (size_t)j*512 + c0);
        float4 wb = *(const float4*)(We + (size_t)j*512 + c0 + 4);
        #pragma unroll
        for (int t = 0; t < 4; ++t) {
            float a = eas[wv*4 + t][j];
            acc[t][0] += a*wa.x; acc[t][1] += a*wa.y; acc[t][2] += a*wa.z; acc[t][3] += a*wa.w;
            acc[t][4] += a*wb.x; acc[t][5] += a*wb.y; acc[t][6] += a*wb.z; acc[t][7] += a*wb.w;
        }
    }
    #pragma unroll
    for (int t = 0; t < 4; ++t) {
        int e = e0 + wv*4 + t;
        if (e >= E) continue;
        int s = src[e], d = dst[e];
        const float* qp = q + (size_t)d*512 + c0;
        const float* kp = k + (size_t)s*512 + c0;
        float4 qa = *(const float4*)qp,      qb2 = *(const float4*)(qp + 4);
        float4 ka = *(const float4*)kp,      kb2 = *(const float4*)(kp + 4);
        float p = qa.x*(ka.x+acc[t][0]) + qa.y*(ka.y+acc[t][1])
                + qa.z*(ka.z+acc[t][2]) + qa.w*(ka.w+acc[t][3])
                + qb2.x*(kb2.x+acc[t][4]) + qb2.y*(kb2.y+acc[t][5])
                + qb2.z*(kb2.z+acc[t][6]) + qb2.w*(kb2.w+acc[t][7]);
        p += __shfl_xor(p, 1);
        p += __shfl_xor(p, 2);
        p += __shfl_xor(p, 4);
        p *= 0.125f;
        if ((lane & 7) == 0) {
            alpha[(size_t)e*8 + head] = p;
            atomicMax(mkey + (size_t)d*8 + head, fkey(p));
        }
    }
}

__global__ void __launch_bounds__(256) k_softmax_ed(
    float* __restrict__ alpha, const unsigned* __restrict__ mkey,
    float* __restrict__ den, const int* __restrict__ dst, int E)
{
    int idx = blockIdx.x * 256 + threadIdx.x;
    if (idx >= E * 8) return;
    int e = idx >> 3, hh = idx & 7;
    int d = dst[e];
    float m = funkey(mkey[(size_t)d*8 + hh]);
    float ex = expf(alpha[idx] - m);
    alpha[idx] = ex;
    atomicAdd(den + (size_t)d*8 + hh, ex);
}

__global__ void __launch_bounds__(256) k_edge_msg(
    const float* __restrict__ ea, const float* __restrict__ v,
    const float* __restrict__ We, const float* __restrict__ be,
    const float* __restrict__ ex, const float* __restrict__ den,
    const int* __restrict__ src, const int* __restrict__ dst,
    float* __restrict__ outmsg, int E)
{
    __shared__ __align__(16) float eas[16][64];
    int tid = threadIdx.x;
    int e0 = blockIdx.x * 16;
    for (int i = tid; i < 1024; i += 256) {
        int r = i >> 6, c = i & 63;
        int rr = e0 + r; if (rr >= E) rr = E - 1;
        eas[r][c] = ea[(size_t)rr * 64 + c];
    }
    __syncthreads();
    int wv = tid >> 6, lane = tid & 63;
    int c0 = lane * 8;
    int head = lane >> 3;
    float acc[4][8];
    float4 b0 = *(const float4*)(be + c0);
    float4 b1 = *(const float4*)(be + c0 + 4);
    #pragma unroll
    for (int t = 0; t < 4; ++t) {
        acc[t][0]=b0.x; acc[t][1]=b0.y; acc[t][2]=b0.z; acc[t][3]=b0.w;
        acc[t][4]=b1.x; acc[t][5]=b1.y; acc[t][6]=b1.z; acc[t][7]=b1.w;
    }
    #pragma unroll 4
    for (int j = 0; j < 64; ++j) {
        float4 wa = *(const float4*)(We + (size_t)j*512 + c0);
        float4 wb = *(const float4*)(We + (size_t)j*512 + c0 + 4);
        #pragma unroll
        for (int t = 0; t < 4; ++t) {
            float a = eas[wv*4 + t][j];
            acc[t][0] += a*wa.x; acc[t][1] += a*wa.y; acc[t][2] += a*wa.z; acc[t][3] += a*wa.w;
            acc[t][4] += a*wb.x; acc[t][5] += a*wb.y; acc[t][6] += a*wb.z; acc[t][7] += a*wb.w;
        }
    }
    #pragma unroll
    for (int t = 0; t < 4; ++t) {
        int e = e0 + wv*4 + t;
        if (e >= E) continue;
        int s = src[e], d = dst[e];
        float a = ex[(size_t)e*8 + head] / (den[(size_t)d*8 + head] + 1e-16f) * 0.125f;
        const float* vp = v + (size_t)s*512 + c0;
        float4 va = *(const float4*)vp, vb2 = *(const float4*)(vp + 4);
        float m[8];
        m[0] = a*(va.x + acc[t][0]); m[1] = a*(va.y + acc[t][1]);
        m[2] = a*(va.z + acc[t][2]); m[3] = a*(va.w + acc[t][3]);
        m[4] = a*(vb2.x + acc[t][4]); m[5] = a*(vb2.y + acc[t][5]);
        m[6] = a*(vb2.z + acc[t][6]); m[7] = a*(vb2.w + acc[t][7]);
        #pragma unroll
        for (int i = 0; i < 8; ++i) {
            m[i] += __shfl_xor(m[i], 8);
            m[i] += __shfl_xor(m[i], 16);
            m[i] += __shfl_xor(m[i], 32);
        }
        if (lane < 8) {
            float* op = outmsg + (size_t)d*64 + lane*8;
            #pragma unroll
            for (int i = 0; i < 8; ++i) atomicAdd(op + i, m[i]);
        }
    }
}

// ---------------- launcher ----------------

extern "C" void kernel_launch(void* const* d_in, const int* in_sizes, int n_in,
                              void* d_out, int out_size, void* d_ws, size_t ws_size,
                              hipStream_t stream)
{
    const float* x         = (const float*)d_in[0];
    const float* edge_attr = (const float*)d_in[1];
    const float* means     = (const float*)d_in[2];
    const float* log_stds  = (const float*)d_in[3];
    const float* spW       = (const float*)d_in[4];
    const float* spb       = (const float*)d_in[5];
    const float* neW       = (const float*)d_in[6];
    const float* neb       = (const float*)d_in[7];
    const float* eeW       = (const float*)d_in[8];
    const float* eeb       = (const float*)d_in[9];
    const float* Wq        = (const float*)d_in[10];
    const float* bq        = (const float*)d_in[11];
    const float* Wk        = (const float*)d_in[12];
    const float* bk        = (const float*)d_in[13];
    const float* Wv        = (const float*)d_in[14];
    const float* bv        = (const float*)d_in[15];
    const float* We        = (const float*)d_in[16];
    const float* be        = (const float*)d_in[17];
    const float* Ws        = (const float*)d_in[18];
    const float* bs        = (const float*)d_in[19];
    const float* euW       = (const float*)d_in[20];
    const float* eub       = (const float*)d_in[21];
    const float* rW1       = (const float*)d_in[22];
    const float* rb1       = (const float*)d_in[23];
    const float* rW2       = (const float*)d_in[24];
    const float* rb2       = (const float*)d_in[25];
    const float* rW3       = (const float*)d_in[26];
    const float* rb3       = (const float*)d_in[27];
    const int* eidx        = (const int*)d_in[28];
    const int* batch       = (const int*)d_in[29];

    int N = in_sizes[0] / 7;
    int E = in_sizes[1] / 4;
    const int G = 32;
    const int* srcp = eidx;
    const int* dstp = eidx + E;

    float* ws = (float*)d_ws;

    // ---- NEW layout ----
    size_t fl = 0;
    float* hA     = ws + fl; fl += (size_t)N * 64;
    float* hB     = ws + fl; fl += (size_t)N * 64;
    float* eaA    = ws + fl; fl += (size_t)E * 64;
    float* eaB    = ws + fl; fl += (size_t)E * 64;
    float* qb_    = ws + fl; fl += (size_t)N * 512;
    float* kb_    = ws + fl; fl += (size_t)N * 512;
    float* vb_    = ws + fl; fl += (size_t)N * 512;
    float* eproj  = ws + fl; fl += (size_t)E * 512;
    float* alpha  = ws + fl; fl += (size_t)E * 8;
    float* outmsg = ws + fl; fl += (size_t)N * 64;
    float* npool  = ws + fl; fl += (size_t)G * 64;
    float* epool  = ws + fl; fl += (size_t)G * 64;
    float* cn     = ws + fl; fl += G;
    float* ce     = ws + fl; fl += G;
    int* ideg  = (int*)(ws + fl); fl += (size_t)N;
    int* iptr  = (int*)(ws + fl); fl += (size_t)N + 1;
    int* ihead = (int*)(ws + fl); fl += (size_t)N;
    int* iperm = (int*)(ws + fl); fl += (size_t)E;
    size_t need_bytes = fl * sizeof(float);

    if (ws_size >= need_bytes) {
        // ================= NEW PATH =================
        hipMemsetAsync(npool, 0, (size_t)(G * 130) * sizeof(float), stream);
        hipMemsetAsync(ideg, 0, (size_t)N * sizeof(int), stream);

        k_node_embed<<<(N * 64 + 255) / 256, 256, 0, stream>>>(x, neW, neb, hA, N);
        k_edge_init<<<(E + 3) / 4, 256, 0, stream>>>(x, edge_attr, means, log_stds,
                                                     spW, spb, eeW, eeb, srcp, dstp, eaA, E);
        k_hist<<<(E + 255) / 256, 256, 0, stream>>>(dstp, ideg, E);
        k_scan<<<1, 1024, 0, stream>>>(ideg, iptr, ihead, N);
        k_scatter<<<(E + 255) / 256, 256, 0, stream>>>(dstp, ihead, iperm, E);

        float* hcur = hA;  float* hnext = hB;
        float* eacur = eaA; float* eanext = eaB;
        for (int l = 0; l < 3; ++l) {
            const float* Wq_l = Wq + (size_t)l * 64 * 512;
            const float* Wk_l = Wk + (size_t)l * 64 * 512;
            const float* Wv_l = Wv + (size_t)l * 64 * 512;
            const float* We_l = We + (size_t)l * 64 * 512;
            k_gemm512_r32<<<(N + 31) / 32, 256, 0, stream>>>(hcur, Wq_l, bq + (size_t)l * 512, qb_, N);
            k_gemm512_r32<<<(N + 31) / 32, 256, 0, stream>>>(hcur, Wk_l, bk + (size_t)l * 512, kb_, N);
            k_gemm512_r32<<<(N + 31) / 32, 256, 0, stream>>>(hcur, Wv_l, bv + (size_t)l * 512, vb_, N);
            k_gemm_e<<<(E + 31) / 32, 256, 0, stream>>>(eacur, We_l, be + (size_t)l * 512,
                                                        qb_, kb_, srcp, dstp, eproj, alpha, E);
            k_attn_node<<<(N + 3) / 4, 256, 0, stream>>>(alpha, eproj, vb_, iptr, iperm, srcp,
                                                         outmsg, N);
            k_node_update<<<(N + 31) / 32, 256, 0, stream>>>(hcur, outmsg, Ws + (size_t)l * 64 * 64,
                                                             bs + (size_t)l * 64, hnext, N);
            k_edge_update<<<(E + 31) / 32, 256, 0, stream>>>(hnext, eacur, euW + (size_t)l * 192 * 64,
                                                             eub + (size_t)l * 64, srcp, dstp, eanext, E);
            float* t1 = hcur; hcur = hnext; hnext = t1;
            float* t2 = eacur; eacur = eanext; eanext = t2;
        }

        k_node_pool<<<(N + 63) / 64, 64, 0, stream>>>(hcur, batch, npool, cn, N);
        k_edge_pool<<<(E + 255) / 256, 256, 0, stream>>>(eacur, srcp, batch, epool, ce, E);
        k_head_mlp<<<G, 64, 0, stream>>>(npool, epool, cn, ce, rW1, rb1, rW2, rb2, rW3, rb3,
                                         (float*)d_out);
    } else {
        // ================= OLD PATH (round-1, proven) =================
        size_t off = 0;
        float* ohA     = ws + off; off += (size_t)N * 64;
        float* ohB     = ws + off; off += (size_t)N * 64;
        float* oeaA    = ws + off; off += (size_t)E * 64;
        float* oeaB    = ws + off; off += (size_t)E * 64;
        float* oqb     = ws + off; off += (size_t)N * 512;
        float* okb     = ws + off; off += (size_t)N * 512;
        float* ovb     = ws + off; off += (size_t)N * 512;
        float* oalpha  = ws + off; off += (size_t)E * 8;
        unsigned* omkey = (unsigned*)(ws + off); off += (size_t)N * 8;
        float* oden    = ws + off; off += (size_t)N * 8;
        float* ooutmsg = ws + off; off += (size_t)N * 64;
        float* onpool  = ws + off; off += (size_t)G * 64;
        float* oepool  = ws + off; off += (size_t)G * 64;
        float* ocn     = ws + off; off += G;
        float* oce     = ws + off; off += G;

        hipMemsetAsync(onpool, 0, (size_t)(G * 130) * sizeof(float), stream);

        k_node_embed<<<(N * 64 + 255) / 256, 256, 0, stream>>>(x, neW, neb, ohA, N);
        k_edge_init<<<(E + 3) / 4, 256, 0, stream>>>(x, edge_attr, means, log_stds,
                                                     spW, spb, eeW, eeb, srcp, dstp, oeaA, E);

        float* hcur = ohA;  float* hnext = ohB;
        float* eacur = oeaA; float* eanext = oeaB;
        for (int l = 0; l < 3; ++l) {
            const float* Wq_l = Wq + (size_t)l * 64 * 512;
            const float* Wk_l = Wk + (size_t)l * 64 * 512;
            const float* Wv_l = Wv + (size_t)l * 64 * 512;
            const float* We_l = We + (size_t)l * 64 * 512;
            k_gemm512<<<(N + 15) / 16, 256, 0, stream>>>(hcur, Wq_l, bq + (size_t)l * 512, oqb, N);
            k_gemm512<<<(N + 15) / 16, 256, 0, stream>>>(hcur, Wk_l, bk + (size_t)l * 512, okb, N);
            k_gemm512<<<(N + 15) / 16, 256, 0, stream>>>(hcur, Wv_l, bv + (size_t)l * 512, ovb, N);
            hipMemsetAsync(omkey, 0, (size_t)N * 80 * sizeof(float), stream);
            k_edge_alpha<<<(E + 15) / 16, 256, 0, stream>>>(eacur, oqb, okb, We_l, be + (size_t)l * 512,
                                                            srcp, dstp, oalpha, omkey, E);
            k_softmax_ed<<<(E * 8 + 255) / 256, 256, 0, stream>>>(oalpha, omkey, oden, dstp, E);
            k_edge_msg<<<(E + 15) / 16, 256, 0, stream>>>(eacur, ovb, We_l, be + (size_t)l * 512,
                                                          oalpha, oden, srcp, dstp, ooutmsg, E);
            k_node_update<<<(N + 31) / 32, 256, 0, stream>>>(hcur, ooutmsg, Ws + (size_t)l * 64 * 64,
                                                             bs + (size_t)l * 64, hnext, N);
            k_edge_update<<<(E + 31) / 32, 256, 0, stream>>>(hnext, eacur, euW + (size_t)l * 192 * 64,
                                                             eub + (size_t)l * 64, srcp, dstp, eanext, E);
            float* t1 = hcur; hcur = hnext; hnext = t1;
            float* t2 = eacur; eacur = eanext; eanext = t2;
        }

        k_node_pool<<<(N + 63) / 64, 64, 0, stream>>>(hcur, batch, onpool, ocn, N);
        k_edge_pool<<<(E + 255) / 256, 256, 0, stream>>>(eacur, srcp, batch, oepool, oce, E);
        k_head_mlp<<<G, 64, 0, stream>>>(onpool, oepool, ocn, oce, rW1, rb1, rW2, rb2, rW3, rb3,
                                         (float*)d_out);
    }
}

// Round 3
// 1509.877 us; speedup vs baseline: 1.3586x; 1.3586x over previous
//
#include <hip/hip_runtime.h>
#include <hip/hip_bf16.h>
#include <cstdint>
#include <cstddef>

// N=20000, E=100000, G=32, HID=64, HEADS=8, HC=64, HO=512, L=3, K=4. All fp32.
// Key identity: e = ea@We + be appears only inside (a) q·(k+e) dots and (b) Σ a(v+e).
//   (a) q·e per head  = ea · qe[dst]   with qe[d][h*64+j] = Σ_c q[d][64h+c] We[j][64h+c]
//   (b) Σ_e a e       = (Σ_e a ea) @ We  (+ (Σ_e a) * be)
// -> all We GEMMs move from E-level to N-level; attention is CSR-fused, atomic-free.
// ws budget: 190.1 MB (known: 194 MB <= ws_size from round 1).

// ---------------- embed / init ----------------

__global__ void __launch_bounds__(256) k_node_embed(
    const float* __restrict__ x, const float* __restrict__ neW, const float* __restrict__ neb,
    float* __restrict__ h, int N)
{
    int idx = blockIdx.x * 256 + threadIdx.x;
    int n = idx >> 6, c = idx & 63;
    if (n >= N) return;
    float acc = neb[c];
    #pragma unroll
    for (int j = 0; j < 7; ++j) acc += x[(size_t)n * 7 + j] * neW[j * 64 + c];
    h[(size_t)n * 64 + c] = fmaxf(acc, 0.f);
}

__global__ void __launch_bounds__(256) k_edge_init(
    const float* __restrict__ x, const float* __restrict__ edge_attr,
    const float* __restrict__ means, const float* __restrict__ log_stds,
    const float* __restrict__ spW, const float* __restrict__ spb,
    const float* __restrict__ eeW, const float* __restrict__ eeb,
    const int* __restrict__ src, const int* __restrict__ dst,
    float* __restrict__ ea, int E)
{
    int gw = (blockIdx.x * 256 + threadIdx.x) >> 6;
    int lane = threadIdx.x & 63;
    if (gw >= E) return;
    int s = src[gw], d = dst[gw];
    const float* ps = x + (size_t)s * 7;
    const float* pd = x + (size_t)d * 7;
    float slx = ps[0], sly = ps[1], srx = ps[2], sry = ps[3];
    float dlx = pd[0], dly = pd[1], drx = pd[2], dry = pd[3];
    float u[8];
    float rx, ry;
    rx = dlx - slx; ry = dly - sly; u[0] = sqrtf(rx*rx + ry*ry); u[1] = atan2f(ry, rx);
    rx = dlx - srx; ry = dly - sry; u[2] = sqrtf(rx*rx + ry*ry); u[3] = atan2f(ry, rx);
    rx = drx - slx; ry = dry - sly; u[4] = sqrtf(rx*rx + ry*ry); u[5] = atan2f(ry, rx);
    rx = drx - srx; ry = dry - sry; u[6] = sqrtf(rx*rx + ry*ry); u[7] = atan2f(ry, rx);
    float w[4];
    #pragma unroll
    for (int kk = 0; kk < 4; ++kk) {
        float ssum = 0.f;
        #pragma unroll
        for (int dd = 0; dd < 8; ++dd) {
            float stdv = expf(log_stds[kk*8+dd]) + 1e-6f;
            float z = (u[dd] - means[kk*8+dd]) / stdv;
            ssum += z * z;
        }
        w[kk] = expf(-0.5f * ssum);
    }
    float accs = spb[lane];
    #pragma unroll
    for (int kk = 0; kk < 4; ++kk) accs += w[kk] * spW[kk*64 + lane];
    float acce = eeb[lane];
    #pragma unroll
    for (int j = 0; j < 4; ++j) acce += edge_attr[(size_t)gw*4 + j] * eeW[j*64 + lane];
    ea[(size_t)gw*64 + lane] = fmaxf(acce, 0.f) + fmaxf(accs, 0.f);
}

// ---------------- CSR build ----------------

__global__ void __launch_bounds__(256) k_hist(
    const int* __restrict__ dst, int* __restrict__ deg, int E)
{
    int e = blockIdx.x * 256 + threadIdx.x;
    if (e < E) atomicAdd(deg + dst[e], 1);
}

__global__ void __launch_bounds__(1024) k_scan(
    const int* __restrict__ deg, int* __restrict__ ptr, int* __restrict__ headw, int N)
{
    __shared__ int part[1024];
    int t = threadIdx.x;
    int per = (N + 1023) / 1024;
    int s = 0;
    for (int i = 0; i < per; ++i) { int idx = t*per + i; if (idx < N) s += deg[idx]; }
    part[t] = s;
    __syncthreads();
    for (int off = 1; off < 1024; off <<= 1) {
        int v = (t >= off) ? part[t - off] : 0;
        __syncthreads();
        part[t] += v;
        __syncthreads();
    }
    int base = (t > 0) ? part[t - 1] : 0;
    for (int i = 0; i < per; ++i) {
        int idx = t*per + i;
        if (idx < N) { ptr[idx] = base; headw[idx] = base; base += deg[idx]; }
    }
    if (t == 1023) ptr[N] = part[1023];
}

__global__ void __launch_bounds__(256) k_scatter(
    const int* __restrict__ dst, int* __restrict__ headw, int* __restrict__ perm, int E)
{
    int e = blockIdx.x * 256 + threadIdx.x;
    if (e < E) {
        int pos = atomicAdd(headw + dst[e], 1);
        perm[pos] = e;
    }
}

// ---------------- GEMMs ----------------

// Y = X @ W + bias  (X: M x 64, W: 64 x 512). BM=32, wave=8 rows, lane=8 cols.
__global__ void __launch_bounds__(256) k_gemm512_r32(
    const float* __restrict__ X, const float* __restrict__ W, const float* __restrict__ bias,
    float* __restrict__ Y, int M)
{
    __shared__ __align__(16) float xs[32][64];
    int tid = threadIdx.x;
    int r0 = blockIdx.x * 32;
    for (int i = tid; i < 2048; i += 256) {
        int r = i >> 6, c = i & 63;
        int rr = r0 + r;
        xs[r][c] = (rr < M) ? X[(size_t)rr * 64 + c] : 0.f;
    }
    __syncthreads();
    int wv = tid >> 6, lane = tid & 63;
    int c0 = lane * 8;
    float acc[8][8];
    float4 b0 = *(const float4*)(bias + c0);
    float4 b1 = *(const float4*)(bias + c0 + 4);
    #pragma unroll
    for (int t = 0; t < 8; ++t) {
        acc[t][0]=b0.x; acc[t][1]=b0.y; acc[t][2]=b0.z; acc[t][3]=b0.w;
        acc[t][4]=b1.x; acc[t][5]=b1.y; acc[t][6]=b1.z; acc[t][7]=b1.w;
    }
    #pragma unroll 2
    for (int j = 0; j < 64; ++j) {
        float4 wa = *(const float4*)(W + (size_t)j*512 + c0);
        float4 wb = *(const float4*)(W + (size_t)j*512 + c0 + 4);
        #pragma unroll
        for (int t = 0; t < 8; ++t) {
            float a = xs[wv*8 + t][j];
            acc[t][0] += a*wa.x; acc[t][1] += a*wa.y; acc[t][2] += a*wa.z; acc[t][3] += a*wa.w;
            acc[t][4] += a*wb.x; acc[t][5] += a*wb.y; acc[t][6] += a*wb.z; acc[t][7] += a*wb.w;
        }
    }
    #pragma unroll
    for (int t = 0; t < 8; ++t) {
        int r = r0 + wv*8 + t;
        if (r < M) {
            float4 o0 = {acc[t][0],acc[t][1],acc[t][2],acc[t][3]};
            float4 o1 = {acc[t][4],acc[t][5],acc[t][6],acc[t][7]};
            *(float4*)(Y + (size_t)r*512 + c0)     = o0;
            *(float4*)(Y + (size_t)r*512 + c0 + 4) = o1;
        }
    }
}

// qe[d][h*64+j] = sum_c q[d][64h+c] * We[j][64h+c].  grid: ((N+31)/32, 8)
__global__ void __launch_bounds__(256) k_qe(
    const float* __restrict__ q, const float* __restrict__ We,
    float* __restrict__ qe, int N)
{
    __shared__ __align__(16) float qlds[32][64];
    __shared__ float welds[64][65];   // +1 pad: conflict-free column reads
    int tid = threadIdx.x;
    int h = blockIdx.y;
    int n0 = blockIdx.x * 32;
    for (int i = tid; i < 2048; i += 256) {
        int r = i >> 6, c = i & 63;
        int n = n0 + r;
        qlds[r][c] = (n < N) ? q[(size_t)n*512 + h*64 + c] : 0.f;
    }
    for (int i = tid; i < 4096; i += 256) {
        int j = i >> 6, c = i & 63;
        welds[j][c] = We[(size_t)j*512 + h*64 + c];
    }
    __syncthreads();
    int wv = tid >> 6, lane = tid & 63;   // lane = j
    float acc[8];
    #pragma unroll
    for (int r = 0; r < 8; ++r) acc[r] = 0.f;
    #pragma unroll 4
    for (int c = 0; c < 64; ++c) {
        float w = welds[lane][c];
        #pragma unroll
        for (int r = 0; r < 8; ++r) acc[r] += qlds[wv*8 + r][c] * w;
    }
    #pragma unroll
    for (int r = 0; r < 8; ++r) {
        int n = n0 + wv*8 + r;
        if (n < N) qe[(size_t)n*512 + h*64 + lane] = acc[r];
    }
}

// ---------------- CSR-fused attention ----------------

// Per node (wave): alpha[e][h] = 0.125*(q[d]·k[s] |_h + ea_e·qe[d] |_h + q[d]·be |_h)
// online max+den per head; writes raw alpha, m, den. No atomics.
__global__ void __launch_bounds__(256) k_attn_alpha(
    const float* __restrict__ q, const float* __restrict__ k, const float* __restrict__ qe,
    const float* __restrict__ be, const float* __restrict__ ea,
    const int* __restrict__ ptr, const int* __restrict__ perm, const int* __restrict__ srcp,
    float* __restrict__ alpha, float* __restrict__ mbuf, float* __restrict__ dbuf, int N)
{
    int wv = threadIdx.x >> 6, lane = threadIdx.x & 63;
    int n = blockIdx.x * 4 + wv;
    if (n >= N) return;
    int h = lane >> 3, p = lane & 7;
    int b = ptr[n], e_ = ptr[n + 1];
    const float4* qp = (const float4*)(q + (size_t)n*512 + lane*8);
    float4 q0 = qp[0], q1 = qp[1];
    const float4* qep = (const float4*)(qe + (size_t)n*512 + lane*8);
    float4 g0 = qep[0], g1 = qep[1];
    const float4* bep = (const float4*)(be + lane*8);
    float4 b0 = bep[0], b1 = bep[1];
    float qbe = q0.x*b0.x + q0.y*b0.y + q0.z*b0.z + q0.w*b0.w
              + q1.x*b1.x + q1.y*b1.y + q1.z*b1.z + q1.w*b1.w;
    qbe += __shfl_xor(qbe, 1);
    qbe += __shfl_xor(qbe, 2);
    qbe += __shfl_xor(qbe, 4);           // all lanes in group h hold q·be|_h
    float m = -3.4e38f, den = 0.f;
    for (int it = b; it < e_; ++it) {
        int e = perm[it];
        int s = srcp[e];
        const float4* kp = (const float4*)(k + (size_t)s*512 + lane*8);
        float4 k0 = kp[0], k1 = kp[1];
        const float4* ap = (const float4*)(ea + (size_t)e*64 + p*8);
        float4 a0 = ap[0], a1 = ap[1];
        float t = q0.x*k0.x + q0.y*k0.y + q0.z*k0.z + q0.w*k0.w
                + q1.x*k1.x + q1.y*k1.y + q1.z*k1.z + q1.w*k1.w
                + a0.x*g0.x + a0.y*g0.y + a0.z*g0.z + a0.w*g0.w
                + a1.x*g1.x + a1.y*g1.y + a1.z*g1.z + a1.w*g1.w;
        t += __shfl_xor(t, 1);
        t += __shfl_xor(t, 2);
        t += __shfl_xor(t, 4);
        float al = 0.125f * (t + qbe);   // 1/sqrt(HC)
        float mn = fmaxf(m, al);
        den = den * expf(m - mn) + expf(al - mn);
        m = mn;
        if (p == 0) alpha[(size_t)e*8 + h] = al;
    }
    if (p == 0) {
        mbuf[(size_t)n*8 + h] = m;
        dbuf[(size_t)n*8 + h] = den;
    }
}

// Per node (wave): a = exp(alpha-m)*0.125/(den+1e-16);
// vagg[c] = Σ a v[src][c];  t[h*64+j] = Σ a_h ea[j];  s_h = Σ a_h.  Coalesced writes.
__global__ void __launch_bounds__(256) k_attn_agg(
    const float* __restrict__ alpha, const float* __restrict__ mbuf, const float* __restrict__ dbuf,
    const float* __restrict__ v, const float* __restrict__ ea,
    const int* __restrict__ ptr, const int* __restrict__ perm, const int* __restrict__ srcp,
    float* __restrict__ vagg, float* __restrict__ tbuf, float* __restrict__ sbuf, int N)
{
    int wv = threadIdx.x >> 6, lane = threadIdx.x & 63;
    int n = blockIdx.x * 4 + wv;
    if (n >= N) return;
    int h = lane >> 3, p = lane & 7;
    int b = ptr[n], e_ = ptr[n + 1];
    float m = mbuf[(size_t)n*8 + h];
    float inv = 0.125f / (dbuf[(size_t)n*8 + h] + 1e-16f);   // 1/HEADS folded in
    float vacc[8], tacc[8];
    #pragma unroll
    for (int i = 0; i < 8; ++i) { vacc[i] = 0.f; tacc[i] = 0.f; }
    float sacc = 0.f;
    for (int it = b; it < e_; ++it) {
        int e = perm[it];
        int s = srcp[e];
        float a = expf(alpha[(size_t)e*8 + h] - m) * inv;
        sacc += a;
        const float4* vp = (const float4*)(v + (size_t)s*512 + lane*8);
        float4 v0 = vp[0], v1 = vp[1];
        const float4* ap = (const float4*)(ea + (size_t)e*64 + p*8);
        float4 a0 = ap[0], a1 = ap[1];
        vacc[0] += a*v0.x; vacc[1] += a*v0.y; vacc[2] += a*v0.z; vacc[3] += a*v0.w;
        vacc[4] += a*v1.x; vacc[5] += a*v1.y; vacc[6] += a*v1.z; vacc[7] += a*v1.w;
        tacc[0] += a*a0.x; tacc[1] += a*a0.y; tacc[2] += a*a0.z; tacc[3] += a*a0.w;
        tacc[4] += a*a1.x; tacc[5] += a*a1.y; tacc[6] += a*a1.z; tacc[7] += a*a1.w;
    }
    float4 o;
    o = {vacc[0],vacc[1],vacc[2],vacc[3]}; *(float4*)(vagg + (size_t)n*512 + lane*8)     = o;
    o = {vacc[4],vacc[5],vacc[6],vacc[7]}; *(float4*)(vagg + (size_t)n*512 + lane*8 + 4) = o;
    o = {tacc[0],tacc[1],tacc[2],tacc[3]}; *(float4*)(tbuf + (size_t)n*512 + lane*8)     = o;
    o = {tacc[4],tacc[5],tacc[6],tacc[7]}; *(float4*)(tbuf + (size_t)n*512 + lane*8 + 4) = o;
    if (p == 0) sbuf[(size_t)n*8 + h] = sacc;
}

// hnext[n][cc] = relu( Σ_h vagg[n][64h+cc] + Σ_j2 t[n][j2] We[j2&63][ (j2>>6)*64+cc ]
//                      + Σ_h s[n][h] be[64h+cc] + (h@Ws)[cc] + bs[cc] )
__global__ void __launch_bounds__(256) k_node_finish(
    const float* __restrict__ vagg, const float* __restrict__ tbuf, const float* __restrict__ sbuf,
    const float* __restrict__ hin, const float* __restrict__ We, const float* __restrict__ be,
    const float* __restrict__ Ws, const float* __restrict__ bs,
    float* __restrict__ hnext, int N)
{
    __shared__ __align__(16) float tlds[16][512];
    __shared__ __align__(16) float hlds[16][64];
    int tid = threadIdx.x;
    int n0 = blockIdx.x * 16;
    for (int i = tid; i < 8192; i += 256) {
        int r = i >> 9, c = i & 511;
        int n = n0 + r;
        tlds[r][c] = (n < N) ? tbuf[(size_t)n*512 + c] : 0.f;
    }
    for (int i = tid; i < 1024; i += 256) {
        int r = i >> 6, c = i & 63;
        int n = n0 + r;
        hlds[r][c] = (n < N) ? hin[(size_t)n*64 + c] : 0.f;
    }
    __syncthreads();
    int wv = tid >> 6, cc = tid & 63;
    float acc[4];
    float bsv = bs[cc];
    #pragma unroll
    for (int r = 0; r < 4; ++r) {
        int n = n0 + wv*4 + r;
        float a = bsv;
        if (n < N) {
            #pragma unroll
            for (int h = 0; h < 8; ++h) {
                a += vagg[(size_t)n*512 + h*64 + cc];
                a += sbuf[(size_t)n*8 + h] * be[h*64 + cc];
            }
        }
        acc[r] = a;
    }
    #pragma unroll 4
    for (int j2 = 0; j2 < 512; ++j2) {
        float w = We[(size_t)(j2 & 63)*512 + (j2 >> 6)*64 + cc];
        #pragma unroll
        for (int r = 0; r < 4; ++r) acc[r] += tlds[wv*4 + r][j2] * w;
    }
    #pragma unroll 4
    for (int j = 0; j < 64; ++j) {
        float w = Ws[(size_t)j*64 + cc];
        #pragma unroll
        for (int r = 0; r < 4; ++r) acc[r] += hlds[wv*4 + r][j] * w;
    }
    #pragma unroll
    for (int r = 0; r < 4; ++r) {
        int n = n0 + wv*4 + r;
        if (n < N) hnext[(size_t)n*64 + cc] = fmaxf(acc[r], 0.f);
    }
}

// ea2 = relu([h[src], h[dst], ea] @ euW + eub)  (192x64)
__global__ void __launch_bounds__(256) k_edge_update(
    const float* __restrict__ h, const float* __restrict__ ea,
    const float* __restrict__ euW, const float* __restrict__ eub,
    const int* __restrict__ src, const int* __restrict__ dst,
    float* __restrict__ ea2, int E)
{
    __shared__ __align__(16) float s_src[32][64];
    __shared__ __align__(16) float s_dst[32][64];
    __shared__ __align__(16) float s_ea[32][64];
    __shared__ int sid[32], did[32];
    int tid = threadIdx.x;
    int e0 = blockIdx.x * 32;
    if (tid < 32) {
        int e = e0 + tid; if (e >= E) e = E - 1;
        sid[tid] = src[e]; did[tid] = dst[e];
    }
    __syncthreads();
    for (int i = tid; i < 2048; i += 256) {
        int r = i >> 6, c = i & 63;
        int e = e0 + r; if (e >= E) e = E - 1;
        s_src[r][c] = h[(size_t)sid[r]*64 + c];
        s_dst[r][c] = h[(size_t)did[r]*64 + c];
        s_ea[r][c]  = ea[(size_t)e*64 + c];
    }
    __syncthreads();
    int wv = tid >> 6, lane = tid & 63;
    float acc[8];
    float bv = eub[lane];
    #pragma unroll
    for (int t = 0; t < 8; ++t) acc[t] = bv;
    #pragma unroll 4
    for (int j = 0; j < 64; ++j) {
        float wval = euW[(size_t)j*64 + lane];
        #pragma unroll
        for (int t = 0; t < 8; ++t) acc[t] += s_src[wv*8 + t][j] * wval;
    }
    #pragma unroll 4
    for (int j = 0; j < 64; ++j) {
        float wval = euW[(size_t)(64 + j)*64 + lane];
        #pragma unroll
        for (int t = 0; t < 8; ++t) acc[t] += s_dst[wv*8 + t][j] * wval;
    }
    #pragma unroll 4
    for (int j = 0; j < 64; ++j) {
        float wval = euW[(size_t)(128 + j)*64 + lane];
        #pragma unroll
        for (int t = 0; t < 8; ++t) acc[t] += s_ea[wv*8 + t][j] * wval;
    }
    #pragma unroll
    for (int t = 0; t < 8; ++t) {
        int e = e0 + wv*8 + t;
        if (e < E) ea2[(size_t)e*64 + lane] = fmaxf(acc[t], 0.f);
    }
}

// ---------------- pooling / head ----------------

__global__ void __launch_bounds__(64) k_node_pool(
    const float* __restrict__ h, const int* __restrict__ batch,
    float* __restrict__ npool, float* __restrict__ cn, int N)
{
    int lane = threadIdx.x;
    int n0 = blockIdx.x * 64;
    float acc = 0.f; int cur = -1; int run = 0;
    for (int i = 0; i < 64; ++i) {
        int n = n0 + i;
        if (n >= N) break;
        int b = batch[n];
        if (b != cur) {
            if (cur >= 0) {
                atomicAdd(npool + (size_t)cur*64 + lane, acc);
                if (lane == 0) atomicAdd(cn + cur, (float)run);
            }
            cur = b; acc = 0.f; run = 0;
        }
        acc += h[(size_t)n*64 + lane];
        ++run;
    }
    if (cur >= 0) {
        atomicAdd(npool + (size_t)cur*64 + lane, acc);
        if (lane == 0) atomicAdd(cn + cur, (float)run);
    }
}

__global__ void __launch_bounds__(256) k_edge_pool(
    const float* __restrict__ ea, const int* __restrict__ src, const int* __restrict__ batch,
    float* __restrict__ epool, float* __restrict__ ce, int E)
{
    __shared__ float pool_s[32][64];
    __shared__ float cnt_s[32];
    int tid = threadIdx.x;
    for (int i = tid; i < 2048; i += 256) ((float*)pool_s)[i] = 0.f;
    if (tid < 32) cnt_s[tid] = 0.f;
    __syncthreads();
    int wv = tid >> 6, lane = tid & 63;
    int base = blockIdx.x * 256 + wv * 64;
    #pragma unroll 4
    for (int i = 0; i < 64; ++i) {
        int e = base + i;
        if (e < E) {
            int b = batch[src[e]];
            float val = ea[(size_t)e*64 + lane];
            atomicAdd(&pool_s[b][lane], val);
            if (lane == 0) atomicAdd(&cnt_s[b], 1.f);
        }
    }
    __syncthreads();
    for (int i = tid; i < 2048; i += 256) atomicAdd(epool + i, ((float*)pool_s)[i]);
    if (tid < 32) atomicAdd(ce + tid, cnt_s[tid]);
}

__global__ void __launch_bounds__(64) k_head_mlp(
    const float* __restrict__ npool, const float* __restrict__ epool,
    const float* __restrict__ cn, const float* __restrict__ ce,
    const float* __restrict__ rW1, const float* __restrict__ rb1,
    const float* __restrict__ rW2, const float* __restrict__ rb2,
    const float* __restrict__ rW3, const float* __restrict__ rb3,
    float* __restrict__ out)
{
    __shared__ float g[128];
    __shared__ float h1[64];
    __shared__ float h2[64];
    int b = blockIdx.x, lane = threadIdx.x;
    float cnv = fmaxf(cn[b], 1.f), cev = fmaxf(ce[b], 1.f);
    g[lane]      = npool[(size_t)b*64 + lane] / cnv;
    g[64 + lane] = epool[(size_t)b*64 + lane] / cev;
    __syncthreads();
    float acc = rb1[lane];
    #pragma unroll 4
    for (int j = 0; j < 128; ++j) acc += g[j] * rW1[j*64 + lane];
    h1[lane] = fmaxf(acc, 0.f);
    __syncthreads();
    acc = rb2[lane];
    #pragma unroll 4
    for (int j = 0; j < 64; ++j) acc += h1[j] * rW2[j*64 + lane];
    h2[lane] = fmaxf(acc, 0.f);
    __syncthreads();
    if (lane < 2) {
        float o = rb3[lane];
        for (int j = 0; j < 64; ++j) o += h2[j] * rW3[j*2 + lane];
        out[b*2 + lane] = tanhf(o);
    }
}

// ---------------- launcher ----------------

extern "C" void kernel_launch(void* const* d_in, const int* in_sizes, int n_in,
                              void* d_out, int out_size, void* d_ws, size_t ws_size,
                              hipStream_t stream)
{
    const float* x         = (const float*)d_in[0];
    const float* edge_attr = (const float*)d_in[1];
    const float* means     = (const float*)d_in[2];
    const float* log_stds  = (const float*)d_in[3];
    const float* spW       = (const float*)d_in[4];
    const float* spb       = (const float*)d_in[5];
    const float* neW       = (const float*)d_in[6];
    const float* neb       = (const float*)d_in[7];
    const float* eeW       = (const float*)d_in[8];
    const float* eeb       = (const float*)d_in[9];
    const float* Wq        = (const float*)d_in[10];
    const float* bq        = (const float*)d_in[11];
    const float* Wk        = (const float*)d_in[12];
    const float* bk        = (const float*)d_in[13];
    const float* Wv        = (const float*)d_in[14];
    const float* bv        = (const float*)d_in[15];
    const float* We        = (const float*)d_in[16];
    const float* be        = (const float*)d_in[17];
    const float* Ws        = (const float*)d_in[18];
    const float* bs        = (const float*)d_in[19];
    const float* euW       = (const float*)d_in[20];
    const float* eub       = (const float*)d_in[21];
    const float* rW1       = (const float*)d_in[22];
    const float* rb1       = (const float*)d_in[23];
    const float* rW2       = (const float*)d_in[24];
    const float* rb2       = (const float*)d_in[25];
    const float* rW3       = (const float*)d_in[26];
    const float* rb3       = (const float*)d_in[27];
    const int* eidx        = (const int*)d_in[28];
    const int* batch       = (const int*)d_in[29];

    int N = in_sizes[0] / 7;
    int E = in_sizes[1] / 4;
    const int G = 32;
    const int* srcp = eidx;
    const int* dstp = eidx + E;

    float* ws = (float*)d_ws;
    size_t fl = 0;
    float* hA    = ws + fl; fl += (size_t)N * 64;
    float* hB    = ws + fl; fl += (size_t)N * 64;
    float* eaA   = ws + fl; fl += (size_t)E * 64;
    float* eaB   = ws + fl; fl += (size_t)E * 64;
    float* B1    = ws + fl; fl += (size_t)N * 512;   // q, then v
    float* B2    = ws + fl; fl += (size_t)N * 512;   // k, then vagg
    float* B3    = ws + fl; fl += (size_t)N * 512;   // qe, then tbuf
    float* alpha = ws + fl; fl += (size_t)E * 8;
    float* mbuf  = ws + fl; fl += (size_t)N * 8;
    float* dbuf  = ws + fl; fl += (size_t)N * 8;
    float* sbuf  = ws + fl; fl += (size_t)N * 8;
    float* npool = ws + fl; fl += (size_t)G * 64;
    float* epool = ws + fl; fl += (size_t)G * 64;
    float* cn    = ws + fl; fl += G;
    float* ce    = ws + fl; fl += G;
    int* ideg  = (int*)(ws + fl); fl += (size_t)N;
    int* iptr  = (int*)(ws + fl); fl += (size_t)N + 1;
    int* ihead = (int*)(ws + fl); fl += (size_t)N;
    int* iperm = (int*)(ws + fl); fl += (size_t)E;
    // total ~47.5M floats = 190.1 MB (ws known >= 194 MB from round 1)

    hipMemsetAsync(npool, 0, (size_t)(G * 130) * sizeof(float), stream);
    hipMemsetAsync(ideg, 0, (size_t)N * sizeof(int), stream);

    k_node_embed<<<(N * 64 + 255) / 256, 256, 0, stream>>>(x, neW, neb, hA, N);
    k_edge_init<<<(E + 3) / 4, 256, 0, stream>>>(x, edge_attr, means, log_stds,
                                                 spW, spb, eeW, eeb, srcp, dstp, eaA, E);
    k_hist<<<(E + 255) / 256, 256, 0, stream>>>(dstp, ideg, E);
    k_scan<<<1, 1024, 0, stream>>>(ideg, iptr, ihead, N);
    k_scatter<<<(E + 255) / 256, 256, 0, stream>>>(dstp, ihead, iperm, E);

    float* hcur = hA;  float* hnext = hB;
    float* eacur = eaA; float* eanext = eaB;
    for (int l = 0; l < 3; ++l) {
        const float* Wq_l = Wq + (size_t)l * 64 * 512;
        const float* Wk_l = Wk + (size_t)l * 64 * 512;
        const float* Wv_l = Wv + (size_t)l * 64 * 512;
        const float* We_l = We + (size_t)l * 64 * 512;
        const float* be_l = be + (size_t)l * 512;

        k_gemm512_r32<<<(N + 31) / 32, 256, 0, stream>>>(hcur, Wq_l, bq + (size_t)l * 512, B1, N);
        k_gemm512_r32<<<(N + 31) / 32, 256, 0, stream>>>(hcur, Wk_l, bk + (size_t)l * 512, B2, N);
        k_qe<<<dim3((N + 31) / 32, 8), 256, 0, stream>>>(B1, We_l, B3, N);
        k_attn_alpha<<<(N + 3) / 4, 256, 0, stream>>>(B1, B2, B3, be_l, eacur,
                                                      iptr, iperm, srcp, alpha, mbuf, dbuf, N);
        k_gemm512_r32<<<(N + 31) / 32, 256, 0, stream>>>(hcur, Wv_l, bv + (size_t)l * 512, B1, N);
        k_attn_agg<<<(N + 3) / 4, 256, 0, stream>>>(alpha, mbuf, dbuf, B1, eacur,
                                                    iptr, iperm, srcp, B2, B3, sbuf, N);
        k_node_finish<<<(N + 15) / 16, 256, 0, stream>>>(B2, B3, sbuf, hcur, We_l, be_l,
                                                         Ws + (size_t)l * 64 * 64,
                                                         bs + (size_t)l * 64, hnext, N);
        k_edge_update<<<(E + 31) / 32, 256, 0, stream>>>(hnext, eacur, euW + (size_t)l * 192 * 64,
                                                         eub + (size_t)l * 64, srcp, dstp, eanext, E);
        float* t1 = hcur; hcur = hnext; hnext = t1;
        float* t2 = eacur; eacur = eanext; eanext = t2;
    }

    k_node_pool<<<(N + 63) / 64, 64, 0, stream>>>(hcur, batch, npool, cn, N);
    k_edge_pool<<<(E + 255) / 256, 256, 0, stream>>>(eacur, srcp, batch, epool, ce, E);
    k_head_mlp<<<G, 64, 0, stream>>>(npool, epool, cn, ce, rW1, rb1, rW2, rb2, rW3, rb3,
                                     (float*)d_out);
}

// Round 4
// 1364.241 us; speedup vs baseline: 1.5036x; 1.1068x over previous
//
#include <hip/hip_runtime.h>
#include <hip/hip_bf16.h>
#include <cstdint>
#include <cstddef>

// N=20000, E=100000, G=32, HID=64, HEADS=8, HC=64, HO=512, L=3, K=4. All fp32.
// Key identity: e = ea@We + be appears only inside (a) q·(k+e) dots and (b) Σ a(v+e).
//   (a) q·e per head  = ea · qe[dst]   with qe[d][h*64+j] = Σ_c q[d][64h+c] We[j][64h+c]
//   (b) Σ_e a e       = (Σ_e a ea) @ We  (+ (Σ_e a) * be)
// Round 4: k_edge_init was 190us @ VALUBusy 110% — 64 lanes redundantly computing
// the same atan2/exp per edge. Split: k_edge_w (1 thread/edge, transcendentals) +
// k_edge_ea (1 thread/col, FMA+store). wbuf aliases alpha (dead at init time).

// ---------------- embed / init ----------------

__global__ void __launch_bounds__(256) k_node_embed(
    const float* __restrict__ x, const float* __restrict__ neW, const float* __restrict__ neb,
    float* __restrict__ h, int N)
{
    int idx = blockIdx.x * 256 + threadIdx.x;
    int n = idx >> 6, c = idx & 63;
    if (n >= N) return;
    float acc = neb[c];
    #pragma unroll
    for (int j = 0; j < 7; ++j) acc += x[(size_t)n * 7 + j] * neW[j * 64 + c];
    h[(size_t)n * 64 + c] = fmaxf(acc, 0.f);
}

// One thread per edge: gaussian RBF weights w[4] from relative geometry.
__global__ void __launch_bounds__(256) k_edge_w(
    const float* __restrict__ x,
    const float* __restrict__ means, const float* __restrict__ log_stds,
    const int* __restrict__ src, const int* __restrict__ dst,
    float* __restrict__ wbuf, int E)
{
    int e = blockIdx.x * 256 + threadIdx.x;
    if (e >= E) return;
    int s = src[e], d = dst[e];
    const float* ps = x + (size_t)s * 7;
    const float* pd = x + (size_t)d * 7;
    float slx = ps[0], sly = ps[1], srx = ps[2], sry = ps[3];
    float dlx = pd[0], dly = pd[1], drx = pd[2], dry = pd[3];
    float u[8];
    float rx, ry;
    rx = dlx - slx; ry = dly - sly; u[0] = sqrtf(rx*rx + ry*ry); u[1] = atan2f(ry, rx);
    rx = dlx - srx; ry = dly - sry; u[2] = sqrtf(rx*rx + ry*ry); u[3] = atan2f(ry, rx);
    rx = drx - slx; ry = dry - sly; u[4] = sqrtf(rx*rx + ry*ry); u[5] = atan2f(ry, rx);
    rx = drx - srx; ry = dry - sry; u[6] = sqrtf(rx*rx + ry*ry); u[7] = atan2f(ry, rx);
    #pragma unroll
    for (int kk = 0; kk < 4; ++kk) {
        float ssum = 0.f;
        #pragma unroll
        for (int dd = 0; dd < 8; ++dd) {
            float stdv = expf(log_stds[kk*8+dd]) + 1e-6f;
            float z = (u[dd] - means[kk*8+dd]) / stdv;
            ssum += z * z;
        }
        wbuf[(size_t)e*4 + kk] = expf(-0.5f * ssum);
    }
}

// One thread per (edge,col): ea = relu(edge_attr@eeW+eeb) + relu(w@spW+spb)
__global__ void __launch_bounds__(256) k_edge_ea(
    const float* __restrict__ edge_attr, const float* __restrict__ wbuf,
    const float* __restrict__ spW, const float* __restrict__ spb,
    const float* __restrict__ eeW, const float* __restrict__ eeb,
    float* __restrict__ ea, int E)
{
    int idx = blockIdx.x * 256 + threadIdx.x;
    int e = idx >> 6, c = idx & 63;
    if (e >= E) return;
    float acce = eeb[c];
    #pragma unroll
    for (int j = 0; j < 4; ++j) acce += edge_attr[(size_t)e*4 + j] * eeW[j*64 + c];
    float accs = spb[c];
    #pragma unroll
    for (int j = 0; j < 4; ++j) accs += wbuf[(size_t)e*4 + j] * spW[j*64 + c];
    ea[(size_t)e*64 + c] = fmaxf(acce, 0.f) + fmaxf(accs, 0.f);
}

// ---------------- CSR build ----------------

__global__ void __launch_bounds__(256) k_hist(
    const int* __restrict__ dst, int* __restrict__ deg, int E)
{
    int e = blockIdx.x * 256 + threadIdx.x;
    if (e < E) atomicAdd(deg + dst[e], 1);
}

__global__ void __launch_bounds__(1024) k_scan(
    const int* __restrict__ deg, int* __restrict__ ptr, int* __restrict__ headw, int N)
{
    __shared__ int part[1024];
    int t = threadIdx.x;
    int per = (N + 1023) / 1024;
    int s = 0;
    for (int i = 0; i < per; ++i) { int idx = t*per + i; if (idx < N) s += deg[idx]; }
    part[t] = s;
    __syncthreads();
    for (int off = 1; off < 1024; off <<= 1) {
        int v = (t >= off) ? part[t - off] : 0;
        __syncthreads();
        part[t] += v;
        __syncthreads();
    }
    int base = (t > 0) ? part[t - 1] : 0;
    for (int i = 0; i < per; ++i) {
        int idx = t*per + i;
        if (idx < N) { ptr[idx] = base; headw[idx] = base; base += deg[idx]; }
    }
    if (t == 1023) ptr[N] = part[1023];
}

__global__ void __launch_bounds__(256) k_scatter(
    const int* __restrict__ dst, int* __restrict__ headw, int* __restrict__ perm, int E)
{
    int e = blockIdx.x * 256 + threadIdx.x;
    if (e < E) {
        int pos = atomicAdd(headw + dst[e], 1);
        perm[pos] = e;
    }
}

// ---------------- GEMMs ----------------

// Y = X @ W + bias  (X: M x 64, W: 64 x 512). BM=32, wave=8 rows, lane=8 cols.
__global__ void __launch_bounds__(256) k_gemm512_r32(
    const float* __restrict__ X, const float* __restrict__ W, const float* __restrict__ bias,
    float* __restrict__ Y, int M)
{
    __shared__ __align__(16) float xs[32][64];
    int tid = threadIdx.x;
    int r0 = blockIdx.x * 32;
    for (int i = tid; i < 2048; i += 256) {
        int r = i >> 6, c = i & 63;
        int rr = r0 + r;
        xs[r][c] = (rr < M) ? X[(size_t)rr * 64 + c] : 0.f;
    }
    __syncthreads();
    int wv = tid >> 6, lane = tid & 63;
    int c0 = lane * 8;
    float acc[8][8];
    float4 b0 = *(const float4*)(bias + c0);
    float4 b1 = *(const float4*)(bias + c0 + 4);
    #pragma unroll
    for (int t = 0; t < 8; ++t) {
        acc[t][0]=b0.x; acc[t][1]=b0.y; acc[t][2]=b0.z; acc[t][3]=b0.w;
        acc[t][4]=b1.x; acc[t][5]=b1.y; acc[t][6]=b1.z; acc[t][7]=b1.w;
    }
    #pragma unroll 2
    for (int j = 0; j < 64; ++j) {
        float4 wa = *(const float4*)(W + (size_t)j*512 + c0);
        float4 wb = *(const float4*)(W + (size_t)j*512 + c0 + 4);
        #pragma unroll
        for (int t = 0; t < 8; ++t) {
            float a = xs[wv*8 + t][j];
            acc[t][0] += a*wa.x; acc[t][1] += a*wa.y; acc[t][2] += a*wa.z; acc[t][3] += a*wa.w;
            acc[t][4] += a*wb.x; acc[t][5] += a*wb.y; acc[t][6] += a*wb.z; acc[t][7] += a*wb.w;
        }
    }
    #pragma unroll
    for (int t = 0; t < 8; ++t) {
        int r = r0 + wv*8 + t;
        if (r < M) {
            float4 o0 = {acc[t][0],acc[t][1],acc[t][2],acc[t][3]};
            float4 o1 = {acc[t][4],acc[t][5],acc[t][6],acc[t][7]};
            *(float4*)(Y + (size_t)r*512 + c0)     = o0;
            *(float4*)(Y + (size_t)r*512 + c0 + 4) = o1;
        }
    }
}

// qe[d][h*64+j] = sum_c q[d][64h+c] * We[j][64h+c].  grid: ((N+31)/32, 8)
__global__ void __launch_bounds__(256) k_qe(
    const float* __restrict__ q, const float* __restrict__ We,
    float* __restrict__ qe, int N)
{
    __shared__ __align__(16) float qlds[32][64];
    __shared__ float welds[64][65];   // +1 pad: conflict-free column reads
    int tid = threadIdx.x;
    int h = blockIdx.y;
    int n0 = blockIdx.x * 32;
    for (int i = tid; i < 2048; i += 256) {
        int r = i >> 6, c = i & 63;
        int n = n0 + r;
        qlds[r][c] = (n < N) ? q[(size_t)n*512 + h*64 + c] : 0.f;
    }
    for (int i = tid; i < 4096; i += 256) {
        int j = i >> 6, c = i & 63;
        welds[j][c] = We[(size_t)j*512 + h*64 + c];
    }
    __syncthreads();
    int wv = tid >> 6, lane = tid & 63;   // lane = j
    float acc[8];
    #pragma unroll
    for (int r = 0; r < 8; ++r) acc[r] = 0.f;
    #pragma unroll 4
    for (int c = 0; c < 64; ++c) {
        float w = welds[lane][c];
        #pragma unroll
        for (int r = 0; r < 8; ++r) acc[r] += qlds[wv*8 + r][c] * w;
    }
    #pragma unroll
    for (int r = 0; r < 8; ++r) {
        int n = n0 + wv*8 + r;
        if (n < N) qe[(size_t)n*512 + h*64 + lane] = acc[r];
    }
}

// ---------------- CSR-fused attention ----------------

__global__ void __launch_bounds__(256) k_attn_alpha(
    const float* __restrict__ q, const float* __restrict__ k, const float* __restrict__ qe,
    const float* __restrict__ be, const float* __restrict__ ea,
    const int* __restrict__ ptr, const int* __restrict__ perm, const int* __restrict__ srcp,
    float* __restrict__ alpha, float* __restrict__ mbuf, float* __restrict__ dbuf, int N)
{
    int wv = threadIdx.x >> 6, lane = threadIdx.x & 63;
    int n = blockIdx.x * 4 + wv;
    if (n >= N) return;
    int h = lane >> 3, p = lane & 7;
    int b = ptr[n], e_ = ptr[n + 1];
    const float4* qp = (const float4*)(q + (size_t)n*512 + lane*8);
    float4 q0 = qp[0], q1 = qp[1];
    const float4* qep = (const float4*)(qe + (size_t)n*512 + lane*8);
    float4 g0 = qep[0], g1 = qep[1];
    const float4* bep = (const float4*)(be + lane*8);
    float4 b0 = bep[0], b1 = bep[1];
    float qbe = q0.x*b0.x + q0.y*b0.y + q0.z*b0.z + q0.w*b0.w
              + q1.x*b1.x + q1.y*b1.y + q1.z*b1.z + q1.w*b1.w;
    qbe += __shfl_xor(qbe, 1);
    qbe += __shfl_xor(qbe, 2);
    qbe += __shfl_xor(qbe, 4);           // all lanes in group h hold q·be|_h
    float m = -3.4e38f, den = 0.f;
    for (int it = b; it < e_; ++it) {
        int e = perm[it];
        int s = srcp[e];
        const float4* kp = (const float4*)(k + (size_t)s*512 + lane*8);
        float4 k0 = kp[0], k1 = kp[1];
        const float4* ap = (const float4*)(ea + (size_t)e*64 + p*8);
        float4 a0 = ap[0], a1 = ap[1];
        float t = q0.x*k0.x + q0.y*k0.y + q0.z*k0.z + q0.w*k0.w
                + q1.x*k1.x + q1.y*k1.y + q1.z*k1.z + q1.w*k1.w
                + a0.x*g0.x + a0.y*g0.y + a0.z*g0.z + a0.w*g0.w
                + a1.x*g1.x + a1.y*g1.y + a1.z*g1.z + a1.w*g1.w;
        t += __shfl_xor(t, 1);
        t += __shfl_xor(t, 2);
        t += __shfl_xor(t, 4);
        float al = 0.125f * (t + qbe);   // 1/sqrt(HC)
        float mn = fmaxf(m, al);
        den = den * expf(m - mn) + expf(al - mn);
        m = mn;
        if (p == 0) alpha[(size_t)e*8 + h] = al;
    }
    if (p == 0) {
        mbuf[(size_t)n*8 + h] = m;
        dbuf[(size_t)n*8 + h] = den;
    }
}

__global__ void __launch_bounds__(256) k_attn_agg(
    const float* __restrict__ alpha, const float* __restrict__ mbuf, const float* __restrict__ dbuf,
    const float* __restrict__ v, const float* __restrict__ ea,
    const int* __restrict__ ptr, const int* __restrict__ perm, const int* __restrict__ srcp,
    float* __restrict__ vagg, float* __restrict__ tbuf, float* __restrict__ sbuf, int N)
{
    int wv = threadIdx.x >> 6, lane = threadIdx.x & 63;
    int n = blockIdx.x * 4 + wv;
    if (n >= N) return;
    int h = lane >> 3, p = lane & 7;
    int b = ptr[n], e_ = ptr[n + 1];
    float m = mbuf[(size_t)n*8 + h];
    float inv = 0.125f / (dbuf[(size_t)n*8 + h] + 1e-16f);   // 1/HEADS folded in
    float vacc[8], tacc[8];
    #pragma unroll
    for (int i = 0; i < 8; ++i) { vacc[i] = 0.f; tacc[i] = 0.f; }
    float sacc = 0.f;
    for (int it = b; it < e_; ++it) {
        int e = perm[it];
        int s = srcp[e];
        float a = expf(alpha[(size_t)e*8 + h] - m) * inv;
        sacc += a;
        const float4* vp = (const float4*)(v + (size_t)s*512 + lane*8);
        float4 v0 = vp[0], v1 = vp[1];
        const float4* ap = (const float4*)(ea + (size_t)e*64 + p*8);
        float4 a0 = ap[0], a1 = ap[1];
        vacc[0] += a*v0.x; vacc[1] += a*v0.y; vacc[2] += a*v0.z; vacc[3] += a*v0.w;
        vacc[4] += a*v1.x; vacc[5] += a*v1.y; vacc[6] += a*v1.z; vacc[7] += a*v1.w;
        tacc[0] += a*a0.x; tacc[1] += a*a0.y; tacc[2] += a*a0.z; tacc[3] += a*a0.w;
        tacc[4] += a*a1.x; tacc[5] += a*a1.y; tacc[6] += a*a1.z; tacc[7] += a*a1.w;
    }
    float4 o;
    o = {vacc[0],vacc[1],vacc[2],vacc[3]}; *(float4*)(vagg + (size_t)n*512 + lane*8)     = o;
    o = {vacc[4],vacc[5],vacc[6],vacc[7]}; *(float4*)(vagg + (size_t)n*512 + lane*8 + 4) = o;
    o = {tacc[0],tacc[1],tacc[2],tacc[3]}; *(float4*)(tbuf + (size_t)n*512 + lane*8)     = o;
    o = {tacc[4],tacc[5],tacc[6],tacc[7]}; *(float4*)(tbuf + (size_t)n*512 + lane*8 + 4) = o;
    if (p == 0) sbuf[(size_t)n*8 + h] = sacc;
}

// hnext[n][cc] = relu( Σ_h vagg[n][64h+cc] + Σ_j2 t[n][j2] We[j2&63][ (j2>>6)*64+cc ]
//                      + Σ_h s[n][h] be[64h+cc] + (h@Ws)[cc] + bs[cc] )
__global__ void __launch_bounds__(256) k_node_finish(
    const float* __restrict__ vagg, const float* __restrict__ tbuf, const float* __restrict__ sbuf,
    const float* __restrict__ hin, const float* __restrict__ We, const float* __restrict__ be,
    const float* __restrict__ Ws, const float* __restrict__ bs,
    float* __restrict__ hnext, int N)
{
    __shared__ __align__(16) float tlds[16][512];
    __shared__ __align__(16) float hlds[16][64];
    int tid = threadIdx.x;
    int n0 = blockIdx.x * 16;
    for (int i = tid; i < 8192; i += 256) {
        int r = i >> 9, c = i & 511;
        int n = n0 + r;
        tlds[r][c] = (n < N) ? tbuf[(size_t)n*512 + c] : 0.f;
    }
    for (int i = tid; i < 1024; i += 256) {
        int r = i >> 6, c = i & 63;
        int n = n0 + r;
        hlds[r][c] = (n < N) ? hin[(size_t)n*64 + c] : 0.f;
    }
    __syncthreads();
    int wv = tid >> 6, cc = tid & 63;
    float acc[4];
    float bsv = bs[cc];
    #pragma unroll
    for (int r = 0; r < 4; ++r) {
        int n = n0 + wv*4 + r;
        float a = bsv;
        if (n < N) {
            #pragma unroll
            for (int h = 0; h < 8; ++h) {
                a += vagg[(size_t)n*512 + h*64 + cc];
                a += sbuf[(size_t)n*8 + h] * be[h*64 + cc];
            }
        }
        acc[r] = a;
    }
    #pragma unroll 4
    for (int j2 = 0; j2 < 512; ++j2) {
        float w = We[(size_t)(j2 & 63)*512 + (j2 >> 6)*64 + cc];
        #pragma unroll
        for (int r = 0; r < 4; ++r) acc[r] += tlds[wv*4 + r][j2] * w;
    }
    #pragma unroll 4
    for (int j = 0; j < 64; ++j) {
        float w = Ws[(size_t)j*64 + cc];
        #pragma unroll
        for (int r = 0; r < 4; ++r) acc[r] += hlds[wv*4 + r][j] * w;
    }
    #pragma unroll
    for (int r = 0; r < 4; ++r) {
        int n = n0 + wv*4 + r;
        if (n < N) hnext[(size_t)n*64 + cc] = fmaxf(acc[r], 0.f);
    }
}

// ea2 = relu([h[src], h[dst], ea] @ euW + eub)  (192x64)
__global__ void __launch_bounds__(256) k_edge_update(
    const float* __restrict__ h, const float* __restrict__ ea,
    const float* __restrict__ euW, const float* __restrict__ eub,
    const int* __restrict__ src, const int* __restrict__ dst,
    float* __restrict__ ea2, int E)
{
    __shared__ __align__(16) float s_src[32][64];
    __shared__ __align__(16) float s_dst[32][64];
    __shared__ __align__(16) float s_ea[32][64];
    __shared__ int sid[32], did[32];
    int tid = threadIdx.x;
    int e0 = blockIdx.x * 32;
    if (tid < 32) {
        int e = e0 + tid; if (e >= E) e = E - 1;
        sid[tid] = src[e]; did[tid] = dst[e];
    }
    __syncthreads();
    for (int i = tid; i < 2048; i += 256) {
        int r = i >> 6, c = i & 63;
        int e = e0 + r; if (e >= E) e = E - 1;
        s_src[r][c] = h[(size_t)sid[r]*64 + c];
        s_dst[r][c] = h[(size_t)did[r]*64 + c];
        s_ea[r][c]  = ea[(size_t)e*64 + c];
    }
    __syncthreads();
    int wv = tid >> 6, lane = tid & 63;
    float acc[8];
    float bv = eub[lane];
    #pragma unroll
    for (int t = 0; t < 8; ++t) acc[t] = bv;
    #pragma unroll 4
    for (int j = 0; j < 64; ++j) {
        float wval = euW[(size_t)j*64 + lane];
        #pragma unroll
        for (int t = 0; t < 8; ++t) acc[t] += s_src[wv*8 + t][j] * wval;
    }
    #pragma unroll 4
    for (int j = 0; j < 64; ++j) {
        float wval = euW[(size_t)(64 + j)*64 + lane];
        #pragma unroll
        for (int t = 0; t < 8; ++t) acc[t] += s_dst[wv*8 + t][j] * wval;
    }
    #pragma unroll 4
    for (int j = 0; j < 64; ++j) {
        float wval = euW[(size_t)(128 + j)*64 + lane];
        #pragma unroll
        for (int t = 0; t < 8; ++t) acc[t] += s_ea[wv*8 + t][j] * wval;
    }
    #pragma unroll
    for (int t = 0; t < 8; ++t) {
        int e = e0 + wv*8 + t;
        if (e < E) ea2[(size_t)e*64 + lane] = fmaxf(acc[t], 0.f);
    }
}

// ---------------- pooling / head ----------------

__global__ void __launch_bounds__(64) k_node_pool(
    const float* __restrict__ h, const int* __restrict__ batch,
    float* __restrict__ npool, float* __restrict__ cn, int N)
{
    int lane = threadIdx.x;
    int n0 = blockIdx.x * 64;
    float acc = 0.f; int cur = -1; int run = 0;
    for (int i = 0; i < 64; ++i) {
        int n = n0 + i;
        if (n >= N) break;
        int b = batch[n];
        if (b != cur) {
            if (cur >= 0) {
                atomicAdd(npool + (size_t)cur*64 + lane, acc);
                if (lane == 0) atomicAdd(cn + cur, (float)run);
            }
            cur = b; acc = 0.f; run = 0;
        }
        acc += h[(size_t)n*64 + lane];
        ++run;
    }
    if (cur >= 0) {
        atomicAdd(npool + (size_t)cur*64 + lane, acc);
        if (lane == 0) atomicAdd(cn + cur, (float)run);
    }
}

__global__ void __launch_bounds__(256) k_edge_pool(
    const float* __restrict__ ea, const int* __restrict__ src, const int* __restrict__ batch,
    float* __restrict__ epool, float* __restrict__ ce, int E)
{
    __shared__ float pool_s[32][64];
    __shared__ float cnt_s[32];
    int tid = threadIdx.x;
    for (int i = tid; i < 2048; i += 256) ((float*)pool_s)[i] = 0.f;
    if (tid < 32) cnt_s[tid] = 0.f;
    __syncthreads();
    int wv = tid >> 6, lane = tid & 63;
    int base = blockIdx.x * 256 + wv * 64;
    #pragma unroll 4
    for (int i = 0; i < 64; ++i) {
        int e = base + i;
        if (e < E) {
            int b = batch[src[e]];
            float val = ea[(size_t)e*64 + lane];
            atomicAdd(&pool_s[b][lane], val);
            if (lane == 0) atomicAdd(&cnt_s[b], 1.f);
        }
    }
    __syncthreads();
    for (int i = tid; i < 2048; i += 256) atomicAdd(epool + i, ((float*)pool_s)[i]);
    if (tid < 32) atomicAdd(ce + tid, cnt_s[tid]);
}

__global__ void __launch_bounds__(64) k_head_mlp(
    const float* __restrict__ npool, const float* __restrict__ epool,
    const float* __restrict__ cn, const float* __restrict__ ce,
    const float* __restrict__ rW1, const float* __restrict__ rb1,
    const float* __restrict__ rW2, const float* __restrict__ rb2,
    const float* __restrict__ rW3, const float* __restrict__ rb3,
    float* __restrict__ out)
{
    __shared__ float g[128];
    __shared__ float h1[64];
    __shared__ float h2[64];
    int b = blockIdx.x, lane = threadIdx.x;
    float cnv = fmaxf(cn[b], 1.f), cev = fmaxf(ce[b], 1.f);
    g[lane]      = npool[(size_t)b*64 + lane] / cnv;
    g[64 + lane] = epool[(size_t)b*64 + lane] / cev;
    __syncthreads();
    float acc = rb1[lane];
    #pragma unroll 4
    for (int j = 0; j < 128; ++j) acc += g[j] * rW1[j*64 + lane];
    h1[lane] = fmaxf(acc, 0.f);
    __syncthreads();
    acc = rb2[lane];
    #pragma unroll 4
    for (int j = 0; j < 64; ++j) acc += h1[j] * rW2[j*64 + lane];
    h2[lane] = fmaxf(acc, 0.f);
    __syncthreads();
    if (lane < 2) {
        float o = rb3[lane];
        for (int j = 0; j < 64; ++j) o += h2[j] * rW3[j*2 + lane];
        out[b*2 + lane] = tanhf(o);
    }
}

// ---------------- launcher ----------------

extern "C" void kernel_launch(void* const* d_in, const int* in_sizes, int n_in,
                              void* d_out, int out_size, void* d_ws, size_t ws_size,
                              hipStream_t stream)
{
    const float* x         = (const float*)d_in[0];
    const float* edge_attr = (const float*)d_in[1];
    const float* means     = (const float*)d_in[2];
    const float* log_stds  = (const float*)d_in[3];
    const float* spW       = (const float*)d_in[4];
    const float* spb       = (const float*)d_in[5];
    const float* neW       = (const float*)d_in[6];
    const float* neb       = (const float*)d_in[7];
    const float* eeW       = (const float*)d_in[8];
    const float* eeb       = (const float*)d_in[9];
    const float* Wq        = (const float*)d_in[10];
    const float* bq        = (const float*)d_in[11];
    const float* Wk        = (const float*)d_in[12];
    const float* bk        = (const float*)d_in[13];
    const float* Wv        = (const float*)d_in[14];
    const float* bv        = (const float*)d_in[15];
    const float* We        = (const float*)d_in[16];
    const float* be        = (const float*)d_in[17];
    const float* Ws        = (const float*)d_in[18];
    const float* bs        = (const float*)d_in[19];
    const float* euW       = (const float*)d_in[20];
    const float* eub       = (const float*)d_in[21];
    const float* rW1       = (const float*)d_in[22];
    const float* rb1       = (const float*)d_in[23];
    const float* rW2       = (const float*)d_in[24];
    const float* rb2       = (const float*)d_in[25];
    const float* rW3       = (const float*)d_in[26];
    const float* rb3       = (const float*)d_in[27];
    const int* eidx        = (const int*)d_in[28];
    const int* batch       = (const int*)d_in[29];

    int N = in_sizes[0] / 7;
    int E = in_sizes[1] / 4;
    const int G = 32;
    const int* srcp = eidx;
    const int* dstp = eidx + E;

    float* ws = (float*)d_ws;
    size_t fl = 0;
    float* hA    = ws + fl; fl += (size_t)N * 64;
    float* hB    = ws + fl; fl += (size_t)N * 64;
    float* eaA   = ws + fl; fl += (size_t)E * 64;
    float* eaB   = ws + fl; fl += (size_t)E * 64;
    float* B1    = ws + fl; fl += (size_t)N * 512;   // q, then v
    float* B2    = ws + fl; fl += (size_t)N * 512;   // k, then vagg
    float* B3    = ws + fl; fl += (size_t)N * 512;   // qe, then tbuf
    float* alpha = ws + fl; fl += (size_t)E * 8;     // also wbuf (E*4) at init
    float* mbuf  = ws + fl; fl += (size_t)N * 8;
    float* dbuf  = ws + fl; fl += (size_t)N * 8;
    float* sbuf  = ws + fl; fl += (size_t)N * 8;
    float* npool = ws + fl; fl += (size_t)G * 64;
    float* epool = ws + fl; fl += (size_t)G * 64;
    float* cn    = ws + fl; fl += G;
    float* ce    = ws + fl; fl += G;
    int* ideg  = (int*)(ws + fl); fl += (size_t)N;
    int* iptr  = (int*)(ws + fl); fl += (size_t)N + 1;
    int* ihead = (int*)(ws + fl); fl += (size_t)N;
    int* iperm = (int*)(ws + fl); fl += (size_t)E;
    // total ~47.5M floats = 190.1 MB (ws known >= 194 MB from round 1)

    float* wbuf = alpha;   // E*4 <= E*8, dead before alpha is first written

    hipMemsetAsync(npool, 0, (size_t)(G * 130) * sizeof(float), stream);
    hipMemsetAsync(ideg, 0, (size_t)N * sizeof(int), stream);

    k_node_embed<<<(N * 64 + 255) / 256, 256, 0, stream>>>(x, neW, neb, hA, N);
    k_edge_w<<<(E + 255) / 256, 256, 0, stream>>>(x, means, log_stds, srcp, dstp, wbuf, E);
    k_edge_ea<<<((size_t)E * 64 + 255) / 256, 256, 0, stream>>>(edge_attr, wbuf,
                                                                spW, spb, eeW, eeb, eaA, E);
    k_hist<<<(E + 255) / 256, 256, 0, stream>>>(dstp, ideg, E);
    k_scan<<<1, 1024, 0, stream>>>(ideg, iptr, ihead, N);
    k_scatter<<<(E + 255) / 256, 256, 0, stream>>>(dstp, ihead, iperm, E);

    float* hcur = hA;  float* hnext = hB;
    float* eacur = eaA; float* eanext = eaB;
    for (int l = 0; l < 3; ++l) {
        const float* Wq_l = Wq + (size_t)l * 64 * 512;
        const float* Wk_l = Wk + (size_t)l * 64 * 512;
        const float* Wv_l = Wv + (size_t)l * 64 * 512;
        const float* We_l = We + (size_t)l * 64 * 512;
        const float* be_l = be + (size_t)l * 512;

        k_gemm512_r32<<<(N + 31) / 32, 256, 0, stream>>>(hcur, Wq_l, bq + (size_t)l * 512, B1, N);
        k_gemm512_r32<<<(N + 31) / 32, 256, 0, stream>>>(hcur, Wk_l, bk + (size_t)l * 512, B2, N);
        k_qe<<<dim3((N + 31) / 32, 8), 256, 0, stream>>>(B1, We_l, B3, N);
        k_attn_alpha<<<(N + 3) / 4, 256, 0, stream>>>(B1, B2, B3, be_l, eacur,
                                                      iptr, iperm, srcp, alpha, mbuf, dbuf, N);
        k_gemm512_r32<<<(N + 31) / 32, 256, 0, stream>>>(hcur, Wv_l, bv + (size_t)l * 512, B1, N);
        k_attn_agg<<<(N + 3) / 4, 256, 0, stream>>>(alpha, mbuf, dbuf, B1, eacur,
                                                    iptr, iperm, srcp, B2, B3, sbuf, N);
        k_node_finish<<<(N + 15) / 16, 256, 0, stream>>>(B2, B3, sbuf, hcur, We_l, be_l,
                                                         Ws + (size_t)l * 64 * 64,
                                                         bs + (size_t)l * 64, hnext, N);
        k_edge_update<<<(E + 31) / 32, 256, 0, stream>>>(hnext, eacur, euW + (size_t)l * 192 * 64,
                                                         eub + (size_t)l * 64, srcp, dstp, eanext, E);
        float* t1 = hcur; hcur = hnext; hnext = t1;
        float* t2 = eacur; eacur = eanext; eanext = t2;
    }

    k_node_pool<<<(N + 63) / 64, 64, 0, stream>>>(hcur, batch, npool, cn, N);
    k_edge_pool<<<(E + 255) / 256, 256, 0, stream>>>(eacur, srcp, batch, epool, ce, E);
    k_head_mlp<<<G, 64, 0, stream>>>(npool, epool, cn, ce, rW1, rb1, rW2, rb2, rW3, rb3,
                                     (float*)d_out);
}